// Round 1
// baseline (670.608 us; speedup 1.0000x reference)
//
#include <hip/hip_runtime.h>
#include <math.h>

#define Dd   512
#define Hh   8
#define Tt   4
#define HDd  64
#define Bb   16
#define Nn   8192
#define HTc  32
#define KS   64
#define NTOK (Bb*Nn)
#define PRUNEc 0.001f
#define EPSc   1e-8f

// ---- workspace byte offsets (total ~18.9 MiB, same footprint as before) ----
#define WS_C1     0u        // 32 f
#define WS_C0     128u      // 32 f
#define WS_M      2048u     // 512 f softmax row max
#define WS_L      4096u     // 512 f softmax row sum
#define WS_TOPW   6144u     // 64*64 f
#define WS_TOPI   22528u    // 64*64 int
#define WS_FLAG   38912u    // int
#define WS_G2H    65536u    // 32*512 bf16 (hi split of g-scaled folded K-proj)
#define WS_G2M    98304u    // 32*512 bf16 (mid)
#define WS_G2L    131072u   // 32*512 bf16 (lo)
#define WS_MEAN   163840u   // 131072 f per-token LN mean
#define WS_INV    688128u   // 131072 f per-token LN rsqrt
#define WS_MASK8  1212416u  // 131072 bytes expanded mask
#define WS_SCORES 2097152u  // 16 MiB scores[b][ht][n]

typedef __attribute__((ext_vector_type(8)))  short short8v;
typedef __attribute__((ext_vector_type(16))) float f32x16;

// bf16x3 split: x ~= h + m + l, each a bf16-representable f32 (trunc splits, exact residuals)
__device__ __forceinline__ void split3(float x, unsigned &h, unsigned &m, unsigned &l){
  unsigned u  = __float_as_uint(x);
  unsigned uh = u & 0xFFFF0000u;
  float rh = x - __uint_as_float(uh);
  unsigned um = __float_as_uint(rh) & 0xFFFF0000u;
  float rm = rh - __uint_as_float(um);
  unsigned ul = __float_as_uint(rm) & 0xFFFF0000u;
  h = uh; m = um; l = ul;
}

// ---------- mask dtype detection (bool may arrive as i32 / u8 / f32) ----------
__global__ void tap_detect(const unsigned* mraw, int* flag){
  int tid = threadIdx.x;
  if (tid == 0) *flag = 0;
  __syncthreads();
  int f = 0;
  for (int i = tid; i < NTOK/4; i += 256){
    unsigned v = mraw[i];
    if (v == 0x3f800000u) f |= 2;
    else if (v & ~1u)     f |= 1;
  }
  if (f) atomicOr(flag, f);
}

__global__ void tap_mask(const void* mraw, const int* flag, unsigned char* m8){
  int i = blockIdx.x*256 + threadIdx.x;
  int fl = *flag;
  unsigned char m;
  if (fl & 2)      m = (((const float*)mraw)[i] != 0.0f);
  else if (fl & 1) m = (((const unsigned char*)mraw)[i] != 0);
  else             m = (((const int*)mraw)[i] != 0);
  m8[i] = m;
}

// ---------- fold query path: G2 (bf16x3 split) [ht][j], C1[ht], C0[ht] ----------
// score[n][ht] = inv_n*(x_n . G2[ht] - mean_n*C1[ht]) + C0[ht]
__global__ void tap_prep(const float* q, const float* ipw, const float* ipb,
                         const float* pre_g, const float* pre_b,
                         const float* q_g, const float* q_b, const float* log_tau,
                         unsigned short* G2h, unsigned short* G2m, unsigned short* G2l,
                         float* C1, float* C0){
  __shared__ float query[Tt][Dd];
  __shared__ float qps[HDd];
  __shared__ float red[256];
  int tid = threadIdx.x;
  int ht = blockIdx.x;           // = h*T + t
  int h = ht >> 2, t = ht & 3;
  float tau = expf(log_tau[0]);
  tau = fminf(fmaxf(tau, 0.1f), 10.0f);
  float itau = 1.0f / tau;
  int wv = tid >> 6, lane = tid & 63;
  { // LN of q rows (wave per row)
    const float* qr = q + wv*Dd;
    float s = 0.f, ss = 0.f;
    for (int j = lane; j < Dd; j += 64){ float x = qr[j]; s += x; ss += x*x; }
    #pragma unroll
    for (int off = 32; off; off >>= 1){ s += __shfl_down(s, off); ss += __shfl_down(ss, off); }
    s = __shfl(s, 0); ss = __shfl(ss, 0);
    float mean = s * (1.f/Dd);
    float var  = ss * (1.f/Dd) - mean*mean;
    float inv  = rsqrtf(var + 1e-5f);
    for (int j = lane; j < Dd; j += 64){
      float x = qr[j];
      query[wv][j] = ((x - mean)*inv*q_g[j] + q_b[j]) * itau;
    }
  }
  __syncthreads();
  { // qp[d] = query[t] . wq[h*64+d] + bq   (4 threads per output)
    int d = tid >> 2, sub = tid & 3;
    int i = h*HDd + d;
    const float* wrow = ipw + (size_t)i*Dd;
    float acc = 0.f;
    int j0 = sub*128;
    for (int j = 0; j < 128; ++j) acc += query[t][j0+j]*wrow[j0+j];
    red[tid] = acc;
    __syncthreads();
    if (sub == 0) qps[d] = red[tid]+red[tid+1]+red[tid+2]+red[tid+3] + ipb[i];
    __syncthreads();
  }
  float c1p = 0.f, c0p = 0.f;
  for (int jj = 0; jj < 2; ++jj){
    int j = tid + jj*256;
    float acc = 0.f;
    #pragma unroll 8
    for (int d = 0; d < HDd; ++d)
      acc += qps[d] * ipw[(size_t)(Dd + h*HDd + d)*Dd + j];
    float w2 = acc * 0.125f;          // 1/sqrt(HD)
    float g2 = w2 * pre_g[j];
    unsigned uh, um, ul;
    split3(g2, uh, um, ul);
    G2h[ht*Dd + j] = (unsigned short)(uh >> 16);
    G2m[ht*Dd + j] = (unsigned short)(um >> 16);
    G2l[ht*Dd + j] = (unsigned short)(ul >> 16);
    // C1 must match the EFFECTIVE g used by the MFMA path (h+m+l)
    float geff = __uint_as_float(uh) + __uint_as_float(um) + __uint_as_float(ul);
    c1p += geff;
    c0p += w2 * pre_b[j];
  }
  if (tid < HDd) c0p += qps[tid] * ipb[Dd + h*HDd + tid] * 0.125f;  // bk term
  red[tid] = c1p; __syncthreads();
  for (int s = 128; s; s >>= 1){ if (tid < s) red[tid] += red[tid+s]; __syncthreads(); }
  if (tid == 0) C1[ht] = red[0];
  __syncthreads();
  red[tid] = c0p; __syncthreads();
  for (int s = 128; s; s >>= 1){ if (tid < s) red[tid] += red[tid+s]; __syncthreads(); }
  if (tid == 0) C0[ht] = red[0];
}

// ---------- main: fused LN-stats + bf16x3-split MFMA scores ----------
// Tile: 128 tokens x 32 ht, K=512 in 8 chunks of 64. Tokens are read once
// (fp32, coalesced), split to 3 bf16 planes in LDS (XOR-swizzled rows so the
// stride-128B ds_read_b128 fragments avoid the 32-way bank conflict).
// A = G2 splits (L2-resident, fragment-loaded straight from global);
// B = token planes from LDS; D[m=ht][n=token] via mfma_f32_32x32x16_bf16.
// 6 split-products (hh,hm,mh,mm,hl,lh) all accumulate into one f32x16 acc
// -> score error ~2^-24 rel (keeps top-64 selection stable).
// C/D map (HW-verified): col = lane&31, row = (reg&3)+8*(reg>>2)+4*(lane>>5).
__global__ __launch_bounds__(256, 2) void tap_scores(
    const float* __restrict__ tokens,
    const unsigned short* __restrict__ G2h, const unsigned short* __restrict__ G2m,
    const unsigned short* __restrict__ G2l,
    const float* __restrict__ C1, const float* __restrict__ C0,
    float* __restrict__ scores, float* __restrict__ meanw, float* __restrict__ invw){
  __shared__ __align__(16) unsigned short xh[128*64];   // 16 KB
  __shared__ __align__(16) unsigned short xm[128*64];   // 16 KB
  __shared__ __align__(16) unsigned short xl[128*64];   // 16 KB
  __shared__ float smean[128], sinv[128];
  __shared__ float c1s[32], c0s[32];
  int tid  = threadIdx.x;
  int lane = tid & 63, wv = tid >> 6;
  size_t t0 = (size_t)blockIdx.x * 128;
  if (tid < 32){ c1s[tid] = C1[tid]; c0s[tid] = C0[tid]; }

  f32x16 acc;
  #pragma unroll
  for (int i = 0; i < 16; ++i) acc[i] = 0.f;

  int trow = tid >> 4;                  // staging row base 0..15
  int tcol = tid & 15;                  // float4 column 0..15
  int brow  = (wv << 5) | (lane & 31);  // this lane's token row in tile (0..127)
  int bhalf = lane >> 5;                // k-half for fragments
  const float4* tokv = (const float4*)(tokens + t0*(size_t)Dd);
  float ps[8], pss[8];
  #pragma unroll
  for (int i = 0; i < 8; ++i){ ps[i] = 0.f; pss[i] = 0.f; }

  for (int c = 0; c < 8; ++c){
    __syncthreads();                    // previous chunk's reads done
    // ---- stage + convert: 128 tok x 64 k fp32 -> 3 bf16 planes; LN partials (exact fp32)
    #pragma unroll
    for (int i = 0; i < 8; ++i){
      int row = trow + (i << 4);
      float4 v = tokv[(size_t)row*128 + c*16 + tcol];
      ps[i]  += v.x + v.y + v.z + v.w;
      pss[i] += v.x*v.x + v.y*v.y + v.z*v.z + v.w*v.w;
      unsigned h0,m0,l0,h1,m1,l1,h2,m2,l2,h3,m3,l3;
      split3(v.x, h0, m0, l0); split3(v.y, h1, m1, l1);
      split3(v.z, h2, m2, l2); split3(v.w, h3, m3, l3);
      int off = row*128 + (((tcol << 3)) ^ ((row & 7) << 4));   // swizzled byte offset
      *(uint2*)((char*)xh + off) = make_uint2((h0>>16)|(h1&0xFFFF0000u), (h2>>16)|(h3&0xFFFF0000u));
      *(uint2*)((char*)xm + off) = make_uint2((m0>>16)|(m1&0xFFFF0000u), (m2>>16)|(m3&0xFFFF0000u));
      *(uint2*)((char*)xl + off) = make_uint2((l0>>16)|(l1&0xFFFF0000u), (l2>>16)|(l3&0xFFFF0000u));
    }
    __syncthreads();
    // ---- 4 k-sub-chunks of 16, 6 split-MFMAs each
    #pragma unroll
    for (int kc = 0; kc < 4; ++kc){
      int boff = brow*128 + ((((kc << 5) | (bhalf << 4))) ^ ((brow & 7) << 4));
      short8v bh = *(const short8v*)((const char*)xh + boff);
      short8v bm = *(const short8v*)((const char*)xm + boff);
      short8v bl = *(const short8v*)((const char*)xl + boff);
      int gi = ((lane & 31) << 9) | (c << 6) | (kc << 4) | (bhalf << 3);
      short8v ah = *(const short8v*)(G2h + gi);
      short8v am = *(const short8v*)(G2m + gi);
      short8v al = *(const short8v*)(G2l + gi);
      acc = __builtin_amdgcn_mfma_f32_32x32x16_bf16(ah, bh, acc, 0, 0, 0);
      acc = __builtin_amdgcn_mfma_f32_32x32x16_bf16(am, bh, acc, 0, 0, 0);
      acc = __builtin_amdgcn_mfma_f32_32x32x16_bf16(ah, bm, acc, 0, 0, 0);
      acc = __builtin_amdgcn_mfma_f32_32x32x16_bf16(am, bm, acc, 0, 0, 0);
      acc = __builtin_amdgcn_mfma_f32_32x32x16_bf16(al, bh, acc, 0, 0, 0);
      acc = __builtin_amdgcn_mfma_f32_32x32x16_bf16(ah, bl, acc, 0, 0, 0);
    }
  }
  // ---- LN stats reduce: 16 staging threads per row, width-16 shuffles
  #pragma unroll
  for (int i = 0; i < 8; ++i){
    float s = ps[i], ss = pss[i];
    #pragma unroll
    for (int off = 8; off; off >>= 1){
      s  += __shfl_down(s,  off, 16);
      ss += __shfl_down(ss, off, 16);
    }
    if (tcol == 0){
      int row = trow + (i << 4);
      float mean = s * (1.f/512.f);
      float var  = ss * (1.f/512.f) - mean*mean;
      float inv  = rsqrtf(var + 1e-5f);
      smean[row] = mean; sinv[row] = inv;
      meanw[t0 + row] = mean; invw[t0 + row] = inv;
    }
  }
  __syncthreads();
  // ---- epilogue: fold LN + C1/C0, store D[ht][token]
  float mean = smean[brow], inv = sinv[brow];
  int b = (int)(t0 >> 13);
  int n = (int)(t0 & 8191) + brow;
  #pragma unroll
  for (int r = 0; r < 16; ++r){
    int ht = (r & 3) + ((r >> 2) << 3) + ((lane >> 5) << 2);
    float sc = inv*(acc[r] - mean*c1s[ht]) + c0s[ht];
    scores[(((size_t)(b*HTc + ht)) << 13) + n] = sc;
  }
}

// ---------- per-(b,h,t) masked softmax normalizers ----------
__global__ void tap_norm(const float* __restrict__ scores, const unsigned char* __restrict__ m8,
                         float* __restrict__ mrow, float* __restrict__ lrow){
  int R = blockIdx.x;                  // b*32 + ht
  int b = R >> 5;
  const float* srow = scores + (size_t)R*Nn;
  const unsigned char* mk = m8 + b*Nn;
  int tid = threadIdx.x;
  int wv = tid >> 6, lane = tid & 63;
  __shared__ float r4[4];
  float v[32];
  float mx = -1e30f;
  #pragma unroll
  for (int i = 0; i < 32; ++i){
    int n = tid + i*256;
    float s = srow[n];
    v[i] = mk[n] ? -1e30f : s;
    mx = fmaxf(mx, v[i]);
  }
  #pragma unroll
  for (int off = 32; off; off >>= 1) mx = fmaxf(mx, __shfl_down(mx, off));
  if (lane == 0) r4[wv] = mx;
  __syncthreads();
  mx = fmaxf(fmaxf(r4[0], r4[1]), fmaxf(r4[2], r4[3]));
  float se = 0.f;
  #pragma unroll
  for (int i = 0; i < 32; ++i) se += expf(v[i] - mx);
  #pragma unroll
  for (int off = 32; off; off >>= 1) se += __shfl_down(se, off);
  __syncthreads();
  if (lane == 0) r4[wv] = se;
  __syncthreads();
  if (tid == 0){ mrow[R] = mx; lrow[R] = r4[0]+r4[1]+r4[2]+r4[3]; }
}

// ---------- per-(b,t): alpha, prune via compaction, fallback, exact top-64 set ----------
__global__ void tap_alpha(const float* __restrict__ scores, const unsigned char* __restrict__ m8,
                          const float* __restrict__ mrow, const float* __restrict__ lrow,
                          float* __restrict__ topw, int* __restrict__ topi){
  __shared__ float av[Nn];            // 32 KB
  __shared__ float lv[1024];
  __shared__ int   li[1024];
  __shared__ float rv[4]; __shared__ int ri[4]; __shared__ int rp[4];
  __shared__ int cnt; __shared__ int sArg;
  int bt = blockIdx.x;
  int b = bt >> 2, t = bt & 3;
  int tid = threadIdx.x;
  int wv = tid >> 6, lane = tid & 63;
  const unsigned char* mk = m8 + b*Nn;
  if (tid == 0) cnt = 0;
  float mh[Hh], il[Hh];
  const float* srows[Hh];
  #pragma unroll
  for (int h = 0; h < Hh; ++h){
    int R = b*HTc + h*Tt + t;
    mh[h] = mrow[R];
    il[h] = 1.0f / lrow[R];
    srows[h] = scores + (size_t)R*Nn;
  }
  float lsum = 0.f;
  float bvv = -2.f; int bii = 1<<30;
  for (int i = 0; i < 32; ++i){
    int n = tid + i*256;
    float a = 0.f;
    if (!mk[n]){
      #pragma unroll
      for (int h = 0; h < Hh; ++h) a += expf(srows[h][n] - mh[h]) * il[h];
      a *= 0.125f;   // mean over heads
    }
    av[n] = a;
    lsum += a;
    float bb = mk[n] ? -1.f : a;
    if (bb > bvv || (bb == bvv && n < bii)){ bvv = bb; bii = n; }
  }
  #pragma unroll
  for (int off = 32; off; off >>= 1) lsum += __shfl_down(lsum, off);
  if (lane == 0) rv[wv] = lsum;
  __syncthreads();
  float Sall = rv[0]+rv[1]+rv[2]+rv[3];
  #pragma unroll
  for (int off = 32; off; off >>= 1){
    float ov = __shfl_down(bvv, off);
    int   oi = __shfl_down(bii, off);
    if (ov > bvv || (ov == bvv && oi < bii)){ bvv = ov; bii = oi; }
  }
  __syncthreads();
  if (lane == 0){ rv[wv] = bvv; ri[wv] = bii; }
  __syncthreads();
  if (tid == 0){
    float bv2 = rv[0]; int bi2 = ri[0];
    for (int w2 = 1; w2 < 4; ++w2)
      if (rv[w2] > bv2 || (rv[w2] == bv2 && ri[w2] < bi2)){ bv2 = rv[w2]; bi2 = ri[w2]; }
    sArg = bi2;
  }
  __syncthreads();
  float f1 = 1.0f / fmaxf(Sall, EPSc);
  for (int i = 0; i < 32; ++i){
    int n = tid + i*256;
    float x = av[n] * f1;
    if (x >= PRUNEc){
      int id = atomicAdd(&cnt, 1);
      if (id < 1024){ lv[id] = x; li[id] = n; }
    }
  }
  __syncthreads();
  int L = cnt;
  float* tw = topw + bt*KS;
  int*   ti = topi + bt*KS;
  if (L == 0){
    if (tid < KS){ tw[tid] = (tid == 0) ? 1.f : 0.f; ti[tid] = (tid == 0) ? sArg : 0; }
    return;
  }
  if (L <= KS){
    if (tid < KS){ tw[tid] = (tid < L) ? lv[tid] : 0.f; ti[tid] = (tid < L) ? li[tid] : 0; }
    return;
  }
  for (int k = 0; k < KS; ++k){
    float bv = -1.f; int bn = 1<<30; int bp = -1;
    for (int j = tid; j < L; j += 256){
      float x = lv[j]; int nn = li[j];
      if (x > bv || (x == bv && nn < bn)){ bv = x; bn = nn; bp = j; }
    }
    #pragma unroll
    for (int off = 32; off; off >>= 1){
      float ov = __shfl_down(bv, off);
      int   on = __shfl_down(bn, off);
      int   op = __shfl_down(bp, off);
      if (ov > bv || (ov == bv && on < bn)){ bv = ov; bn = on; bp = op; }
    }
    if (lane == 0){ rv[wv] = bv; ri[wv] = bn; rp[wv] = bp; }
    __syncthreads();
    if (tid == 0){
      float bb = rv[0]; int bj = ri[0]; int pp = rp[0];
      for (int w2 = 1; w2 < 4; ++w2)
        if (rv[w2] > bb || (rv[w2] == bb && ri[w2] < bj)){ bb = rv[w2]; bj = ri[w2]; pp = rp[w2]; }
      tw[k] = bb; ti[k] = bj;
      lv[pp] = -1.f;
    }
    __syncthreads();
  }
}

// ---------- pooling: u = sum_k w_k*normed_k (LN folded via saved stats), then u@wv^T ----------
__global__ void tap_pool(const float* __restrict__ tokens, const float* __restrict__ ipw,
                         const float* __restrict__ ipb,
                         const float* __restrict__ pre_g, const float* __restrict__ pre_b,
                         const float* __restrict__ meanw, const float* __restrict__ invw,
                         const float* __restrict__ topw, const int* __restrict__ topi,
                         float* __restrict__ out){
  __shared__ float wk_[KS]; __shared__ int rk_[KS];
  __shared__ float coeff[KS];
  __shared__ __align__(16) float u[Dd];
  __shared__ float sW, sS;
  int bt = blockIdx.x;
  int b = bt >> 2;
  int tid = threadIdx.x;
  if (tid < KS){ wk_[tid] = topw[bt*KS + tid]; rk_[tid] = topi[bt*KS + tid]; }
  __syncthreads();
  if (tid < KS){
    float v = wk_[tid];
    #pragma unroll
    for (int off = 32; off; off >>= 1) v += __shfl_down(v, off);
    if (tid == 0) sW = v;
  }
  __syncthreads();
  float sumw = sW;
  float Winv = 1.0f / fmaxf(sumw, EPSc);
  float Wn   = sumw * Winv;
  if (tid < KS){
    int n = rk_[tid];
    float mk = meanw[(size_t)b*Nn + n];
    float ik = invw [(size_t)b*Nn + n];
    float wn = wk_[tid] * Winv;
    coeff[tid] = wn * ik;
    float sp = wn * mk * ik;
    #pragma unroll
    for (int off = 32; off; off >>= 1) sp += __shfl_down(sp, off);
    if (tid == 0) sS = sp;
  }
  __syncthreads();
  float Sv = sS;
  int d0 = tid, d1 = tid + 256;
  float acc0 = 0.f, acc1 = 0.f;
  #pragma unroll 4
  for (int k = 0; k < KS; ++k){
    float c = coeff[k];
    const float* xr = tokens + ((size_t)b*Nn + rk_[k])*Dd;
    acc0 = fmaf(c, xr[d0], acc0);
    acc1 = fmaf(c, xr[d1], acc1);
  }
  u[d0] = pre_g[d0]*(acc0 - Sv) + pre_b[d0]*Wn;
  u[d1] = pre_g[d1]*(acc1 - Sv) + pre_b[d1]*Wn;
  __syncthreads();
  const float4* u4 = (const float4*)u;
  const float4* w0 = (const float4*)(ipw + (size_t)(2*Dd + d0)*Dd);
  const float4* w1 = (const float4*)(ipw + (size_t)(2*Dd + d1)*Dd);
  float o0 = 0.f, o1 = 0.f;
  #pragma unroll 4
  for (int j4 = 0; j4 < 128; ++j4){
    float4 uu = u4[j4];
    float4 a = w0[j4], c = w1[j4];
    o0 += uu.x*a.x + uu.y*a.y + uu.z*a.z + uu.w*a.w;
    o1 += uu.x*c.x + uu.y*c.y + uu.z*c.z + uu.w*c.w;
  }
  out[bt*Dd + d0] = o0 + Wn*ipb[2*Dd + d0];
  out[bt*Dd + d1] = o1 + Wn*ipb[2*Dd + d1];
}

extern "C" void kernel_launch(void* const* d_in, const int* in_sizes, int n_in,
                              void* d_out, int out_size, void* d_ws, size_t ws_size,
                              hipStream_t stream){
  const float* tokens = (const float*)d_in[0];
  const void*  kpm    = d_in[1];
  const float* q      = (const float*)d_in[2];
  const float* ipw    = (const float*)d_in[3];
  const float* ipb    = (const float*)d_in[4];
  const float* pre_g  = (const float*)d_in[5];
  const float* pre_b  = (const float*)d_in[6];
  const float* q_g    = (const float*)d_in[7];
  const float* q_b    = (const float*)d_in[8];
  const float* ltau   = (const float*)d_in[9];
  char* ws = (char*)d_ws;
  float* C1    = (float*)(ws + WS_C1);
  float* C0    = (float*)(ws + WS_C0);
  float* mrow  = (float*)(ws + WS_M);
  float* lrow  = (float*)(ws + WS_L);
  float* topwv = (float*)(ws + WS_TOPW);
  int*   topiv = (int*)  (ws + WS_TOPI);
  int*   flag  = (int*)  (ws + WS_FLAG);
  unsigned short* G2h = (unsigned short*)(ws + WS_G2H);
  unsigned short* G2m = (unsigned short*)(ws + WS_G2M);
  unsigned short* G2l = (unsigned short*)(ws + WS_G2L);
  float* meanw = (float*)(ws + WS_MEAN);
  float* invw  = (float*)(ws + WS_INV);
  unsigned char* m8 = (unsigned char*)(ws + WS_MASK8);
  float* scores = (float*)(ws + WS_SCORES);
  float* out = (float*)d_out;

  hipLaunchKernelGGL(tap_detect, dim3(1), dim3(256), 0, stream, (const unsigned*)kpm, flag);
  hipLaunchKernelGGL(tap_mask,   dim3(NTOK/256), dim3(256), 0, stream, kpm, flag, m8);
  hipLaunchKernelGGL(tap_prep,   dim3(HTc), dim3(256), 0, stream,
                     q, ipw, ipb, pre_g, pre_b, q_g, q_b, ltau, G2h, G2m, G2l, C1, C0);
  hipLaunchKernelGGL(tap_scores, dim3(NTOK/128), dim3(256), 0, stream,
                     tokens, G2h, G2m, G2l, C1, C0, scores, meanw, invw);
  hipLaunchKernelGGL(tap_norm,   dim3(Bb*HTc), dim3(256), 0, stream, scores, m8, mrow, lrow);
  hipLaunchKernelGGL(tap_alpha,  dim3(Bb*Tt), dim3(256), 0, stream,
                     scores, m8, mrow, lrow, topwv, topiv);
  hipLaunchKernelGGL(tap_pool,   dim3(Bb*Tt), dim3(256), 0, stream,
                     tokens, ipw, ipb, pre_g, pre_b, meanw, invw, topwv, topiv, out);
}

// Round 2
// 604.735 us; speedup vs baseline: 1.1089x; 1.1089x over previous
//
#include <hip/hip_runtime.h>
#include <math.h>

#define Dd   512
#define Hh   8
#define Tt   4
#define HDd  64
#define Bb   16
#define Nn   8192
#define HTc  32
#define KS   64
#define NTOK (Bb*Nn)
#define PRUNEc 0.001f
#define EPSc   1e-8f

// ---- workspace byte offsets (total ~18.9 MiB) ----
#define WS_C1     0u        // 32 f
#define WS_C0     128u      // 32 f
#define WS_M      2048u     // 512 f softmax row max
#define WS_L      4096u     // 512 f softmax row sum
#define WS_TOPW   6144u     // 64*64 f
#define WS_TOPI   22528u    // 64*64 int
#define WS_FLAG   38912u    // int
#define WS_G2H    65536u    // 32*512 bf16 (hi split of g-scaled folded K-proj)
#define WS_G2M    98304u    // 32*512 bf16 (mid)
#define WS_G2L    131072u   // 32*512 bf16 (lo)
#define WS_MEAN   163840u   // 131072 f per-token LN mean
#define WS_INV    688128u   // 131072 f per-token LN rsqrt
#define WS_MASK8  1212416u  // 131072 bytes expanded mask
#define WS_SCORES 2097152u  // 16 MiB scores[b][ht][n]

typedef __attribute__((ext_vector_type(8)))  short short8v;
typedef __attribute__((ext_vector_type(16))) float f32x16;

// bf16x3 split: x ~= h + m + l, each bf16-representable (trunc splits, exact residuals)
__device__ __forceinline__ void split3(float x, unsigned &h, unsigned &m, unsigned &l){
  unsigned u  = __float_as_uint(x);
  unsigned uh = u & 0xFFFF0000u;
  float rh = x - __uint_as_float(uh);
  unsigned um = __float_as_uint(rh) & 0xFFFF0000u;
  float rm = rh - __uint_as_float(um);
  unsigned ul = __float_as_uint(rm) & 0xFFFF0000u;
  h = uh; m = um; l = ul;
}

// 8 fp32 -> 3 bf16x8 fragment planes, fully in registers
__device__ __forceinline__ void split3x8(float4 v0, float4 v1,
                                         short8v &h, short8v &m, short8v &l){
  union { short8v s; unsigned u[4]; } H, M, L;
  float a[8] = {v0.x,v0.y,v0.z,v0.w,v1.x,v1.y,v1.z,v1.w};
  #pragma unroll
  for (int w = 0; w < 4; ++w){
    unsigned ha, ma, la, hb, mb, lb;
    split3(a[2*w],   ha, ma, la);
    split3(a[2*w+1], hb, mb, lb);
    H.u[w] = (ha>>16) | (hb & 0xFFFF0000u);
    M.u[w] = (ma>>16) | (mb & 0xFFFF0000u);
    L.u[w] = (la>>16) | (lb & 0xFFFF0000u);
  }
  h = H.s; m = M.s; l = L.s;
}

// ---------- mask dtype detection (bool may arrive as i32 / u8 / f32) ----------
__device__ __forceinline__ int chkw(unsigned v){
  return (v == 0x3f800000u) ? 2 : ((v & ~1u) ? 1 : 0);
}
__global__ void tap_detect(const uint4* mraw, int* flag){
  int tid = threadIdx.x;            // 1024 threads
  if (tid == 0) *flag = 0;
  __syncthreads();
  int f = 0;
  #pragma unroll
  for (int i = 0; i < 8; ++i){      // 8192 uint4 = first NTOK bytes
    uint4 v = mraw[tid + i*1024];
    f |= chkw(v.x) | chkw(v.y) | chkw(v.z) | chkw(v.w);
  }
  if (f) atomicOr(flag, f);
}

__global__ void tap_mask(const void* mraw, const int* flag, unsigned char* m8){
  int i = blockIdx.x*256 + threadIdx.x;
  int fl = *flag;
  unsigned char m;
  if (fl & 2)      m = (((const float*)mraw)[i] != 0.0f);
  else if (fl & 1) m = (((const unsigned char*)mraw)[i] != 0);
  else             m = (((const int*)mraw)[i] != 0);
  m8[i] = m;
}

// ---------- fold query path: G2 (bf16x3 split) [ht][j], C1[ht], C0[ht] ----------
// score[n][ht] = inv_n*(x_n . G2[ht] - mean_n*C1[ht]) + C0[ht]
__global__ void tap_prep(const float* q, const float* ipw, const float* ipb,
                         const float* pre_g, const float* pre_b,
                         const float* q_g, const float* q_b, const float* log_tau,
                         unsigned short* G2h, unsigned short* G2m, unsigned short* G2l,
                         float* C1, float* C0){
  __shared__ float query[Tt][Dd];
  __shared__ float qps[HDd];
  __shared__ float red[256];
  int tid = threadIdx.x;
  int ht = blockIdx.x;           // = h*T + t
  int h = ht >> 2, t = ht & 3;
  float tau = expf(log_tau[0]);
  tau = fminf(fmaxf(tau, 0.1f), 10.0f);
  float itau = 1.0f / tau;
  int wv = tid >> 6, lane = tid & 63;
  { // LN of q rows (wave per row)
    const float* qr = q + wv*Dd;
    float s = 0.f, ss = 0.f;
    for (int j = lane; j < Dd; j += 64){ float x = qr[j]; s += x; ss += x*x; }
    #pragma unroll
    for (int off = 32; off; off >>= 1){ s += __shfl_down(s, off); ss += __shfl_down(ss, off); }
    s = __shfl(s, 0); ss = __shfl(ss, 0);
    float mean = s * (1.f/Dd);
    float var  = ss * (1.f/Dd) - mean*mean;
    float inv  = rsqrtf(var + 1e-5f);
    for (int j = lane; j < Dd; j += 64){
      float x = qr[j];
      query[wv][j] = ((x - mean)*inv*q_g[j] + q_b[j]) * itau;
    }
  }
  __syncthreads();
  { // qp[d] = query[t] . wq[h*64+d] + bq   (4 threads per output)
    int d = tid >> 2, sub = tid & 3;
    int i = h*HDd + d;
    const float* wrow = ipw + (size_t)i*Dd;
    float acc = 0.f;
    int j0 = sub*128;
    for (int j = 0; j < 128; ++j) acc += query[t][j0+j]*wrow[j0+j];
    red[tid] = acc;
    __syncthreads();
    if (sub == 0) qps[d] = red[tid]+red[tid+1]+red[tid+2]+red[tid+3] + ipb[i];
    __syncthreads();
  }
  float c1p = 0.f, c0p = 0.f;
  for (int jj = 0; jj < 2; ++jj){
    int j = tid + jj*256;
    float acc = 0.f;
    #pragma unroll 8
    for (int d = 0; d < HDd; ++d)
      acc += qps[d] * ipw[(size_t)(Dd + h*HDd + d)*Dd + j];
    float w2 = acc * 0.125f;          // 1/sqrt(HD)
    float g2 = w2 * pre_g[j];
    unsigned uh, um, ul;
    split3(g2, uh, um, ul);
    G2h[ht*Dd + j] = (unsigned short)(uh >> 16);
    G2m[ht*Dd + j] = (unsigned short)(um >> 16);
    G2l[ht*Dd + j] = (unsigned short)(ul >> 16);
    // C1 must match the EFFECTIVE g used by the MFMA path (h+m+l)
    float geff = __uint_as_float(uh) + __uint_as_float(um) + __uint_as_float(ul);
    c1p += geff;
    c0p += w2 * pre_b[j];
  }
  if (tid < HDd) c0p += qps[tid] * ipb[Dd + h*HDd + tid] * 0.125f;  // bk term
  red[tid] = c1p; __syncthreads();
  for (int s = 128; s; s >>= 1){ if (tid < s) red[tid] += red[tid+s]; __syncthreads(); }
  if (tid == 0) C1[ht] = red[0];
  __syncthreads();
  red[tid] = c0p; __syncthreads();
  for (int s = 128; s; s >>= 1){ if (tid < s) red[tid] += red[tid+s]; __syncthreads(); }
  if (tid == 0) C0[ht] = red[0];
}

// ---------- main: LDS-free streaming bf16x3 MFMA scores ----------
// Tile: 128 tokens x 32 ht per block (4 waves, one 32x32 MFMA tile each).
// B-fragments (8 consecutive k of one token row) load straight from global
// as 2x float4 (lanes l / l+32 share a row -> 64 B contiguous per row per
// instr, full cacheline use); split3 -> bf16 planes in registers. A (G2
// splits, 96 KB) is L1/L2-resident. No LDS, no barriers -> no block-wide
// latency stalls; 4 blocks/CU.  LN stats: each lane owns half its row,
// one shfl_xor(32) merges siblings.
// C/D map (HW-verified): col(token) = lane&31, row(ht) = (r&3)+8*(r>>2)+4*(lane>>5).
__global__ __launch_bounds__(256, 4) void tap_scores(
    const float* __restrict__ tokens,
    const unsigned short* __restrict__ G2h, const unsigned short* __restrict__ G2m,
    const unsigned short* __restrict__ G2l,
    const float* __restrict__ C1, const float* __restrict__ C0,
    float* __restrict__ scores, float* __restrict__ meanw, float* __restrict__ invw){
  int tid   = threadIdx.x;
  int lane  = tid & 63, wv = tid >> 6;
  int col   = lane & 31;
  int bhalf = lane >> 5;
  size_t t0 = (size_t)blockIdx.x * 128;
  int brow  = (wv << 5) | col;           // this lane's token row in tile
  const float* __restrict__ xrow = tokens + (t0 + brow)*(size_t)Dd;
  int abase = (col << 9) | (bhalf << 3); // A row = ht = col, k-half offset

  f32x16 acc;
  #pragma unroll
  for (int i = 0; i < 16; ++i) acc[i] = 0.f;
  float ps = 0.f, pss = 0.f;

  for (int c = 0; c < 8; ++c){
    #pragma unroll
    for (int kc = 0; kc < 4; ++kc){
      int k0 = (c << 6) | (kc << 4) | (bhalf << 3);
      float4 v0 = *(const float4*)(xrow + k0);
      float4 v1 = *(const float4*)(xrow + k0 + 4);
      int ga = abase + (c << 6) + (kc << 4);
      short8v ah = *(const short8v*)(G2h + ga);
      short8v am = *(const short8v*)(G2m + ga);
      short8v al = *(const short8v*)(G2l + ga);
      ps  += v0.x+v0.y+v0.z+v0.w + v1.x+v1.y+v1.z+v1.w;
      pss += v0.x*v0.x+v0.y*v0.y+v0.z*v0.z+v0.w*v0.w
           + v1.x*v1.x+v1.y*v1.y+v1.z*v1.z+v1.w*v1.w;
      short8v bh, bm, bl;
      split3x8(v0, v1, bh, bm, bl);
      acc = __builtin_amdgcn_mfma_f32_32x32x16_bf16(ah, bh, acc, 0, 0, 0);
      acc = __builtin_amdgcn_mfma_f32_32x32x16_bf16(am, bh, acc, 0, 0, 0);
      acc = __builtin_amdgcn_mfma_f32_32x32x16_bf16(ah, bm, acc, 0, 0, 0);
      acc = __builtin_amdgcn_mfma_f32_32x32x16_bf16(am, bm, acc, 0, 0, 0);
      acc = __builtin_amdgcn_mfma_f32_32x32x16_bf16(al, bh, acc, 0, 0, 0);
      acc = __builtin_amdgcn_mfma_f32_32x32x16_bf16(ah, bl, acc, 0, 0, 0);
    }
  }
  // LN stats: merge with k-half sibling (lane ^ 32), then finalize per-lane
  ps  += __shfl_xor(ps, 32);
  pss += __shfl_xor(pss, 32);
  float mean = ps * (1.f/512.f);
  float var  = pss * (1.f/512.f) - mean*mean;
  float inv  = rsqrtf(var + 1e-5f);
  if (bhalf == 0){ meanw[t0 + brow] = mean; invw[t0 + brow] = inv; }
  int b = (int)(t0 >> 13);
  int n = (int)(t0 & 8191) + brow;
  #pragma unroll
  for (int r = 0; r < 16; ++r){
    int ht = (r & 3) + ((r >> 2) << 3) + (bhalf << 2);
    float sc = inv*(acc[r] - mean*C1[ht]) + C0[ht];
    scores[(((size_t)(b*HTc + ht)) << 13) + n] = sc;
  }
}

// ---------- per-(b,h,t) masked softmax normalizers ----------
__global__ void tap_norm(const float* __restrict__ scores, const unsigned char* __restrict__ m8,
                         float* __restrict__ mrow, float* __restrict__ lrow){
  int R = blockIdx.x;                  // b*32 + ht
  int b = R >> 5;
  const float* srow = scores + (size_t)R*Nn;
  const unsigned char* mk = m8 + b*Nn;
  int tid = threadIdx.x;
  int wv = tid >> 6, lane = tid & 63;
  __shared__ float r4[4];
  float v[32];
  float mx = -1e30f;
  #pragma unroll
  for (int i = 0; i < 32; ++i){
    int n = tid + i*256;
    float s = srow[n];
    v[i] = mk[n] ? -1e30f : s;
    mx = fmaxf(mx, v[i]);
  }
  #pragma unroll
  for (int off = 32; off; off >>= 1) mx = fmaxf(mx, __shfl_down(mx, off));
  if (lane == 0) r4[wv] = mx;
  __syncthreads();
  mx = fmaxf(fmaxf(r4[0], r4[1]), fmaxf(r4[2], r4[3]));
  float se = 0.f;
  #pragma unroll
  for (int i = 0; i < 32; ++i) se += expf(v[i] - mx);
  #pragma unroll
  for (int off = 32; off; off >>= 1) se += __shfl_down(se, off);
  __syncthreads();
  if (lane == 0) r4[wv] = se;
  __syncthreads();
  if (tid == 0){ mrow[R] = mx; lrow[R] = r4[0]+r4[1]+r4[2]+r4[3]; }
}

// ---------- per-(b,t): alpha, prune via compaction, fallback, exact top-64 set ----------
__global__ void tap_alpha(const float* __restrict__ scores, const unsigned char* __restrict__ m8,
                          const float* __restrict__ mrow, const float* __restrict__ lrow,
                          float* __restrict__ topw, int* __restrict__ topi){
  __shared__ float av[Nn];            // 32 KB
  __shared__ float lv[1024];
  __shared__ int   li[1024];
  __shared__ float rv[4]; __shared__ int ri[4]; __shared__ int rp[4];
  __shared__ int cnt; __shared__ int sArg;
  int bt = blockIdx.x;
  int b = bt >> 2, t = bt & 3;
  int tid = threadIdx.x;
  int wv = tid >> 6, lane = tid & 63;
  const unsigned char* mk = m8 + b*Nn;
  if (tid == 0) cnt = 0;
  float mh[Hh], il[Hh];
  const float* srows[Hh];
  #pragma unroll
  for (int h = 0; h < Hh; ++h){
    int R = b*HTc + h*Tt + t;
    mh[h] = mrow[R];
    il[h] = 1.0f / lrow[R];
    srows[h] = scores + (size_t)R*Nn;
  }
  float lsum = 0.f;
  float bvv = -2.f; int bii = 1<<30;
  for (int i = 0; i < 32; ++i){
    int n = tid + i*256;
    float a = 0.f;
    if (!mk[n]){
      #pragma unroll
      for (int h = 0; h < Hh; ++h) a += expf(srows[h][n] - mh[h]) * il[h];
      a *= 0.125f;   // mean over heads
    }
    av[n] = a;
    lsum += a;
    float bb = mk[n] ? -1.f : a;
    if (bb > bvv || (bb == bvv && n < bii)){ bvv = bb; bii = n; }
  }
  #pragma unroll
  for (int off = 32; off; off >>= 1) lsum += __shfl_down(lsum, off);
  if (lane == 0) rv[wv] = lsum;
  __syncthreads();
  float Sall = rv[0]+rv[1]+rv[2]+rv[3];
  #pragma unroll
  for (int off = 32; off; off >>= 1){
    float ov = __shfl_down(bvv, off);
    int   oi = __shfl_down(bii, off);
    if (ov > bvv || (ov == bvv && oi < bii)){ bvv = ov; bii = oi; }
  }
  __syncthreads();
  if (lane == 0){ rv[wv] = bvv; ri[wv] = bii; }
  __syncthreads();
  if (tid == 0){
    float bv2 = rv[0]; int bi2 = ri[0];
    for (int w2 = 1; w2 < 4; ++w2)
      if (rv[w2] > bv2 || (rv[w2] == bv2 && ri[w2] < bi2)){ bv2 = rv[w2]; bi2 = ri[w2]; }
    sArg = bi2;
  }
  __syncthreads();
  float f1 = 1.0f / fmaxf(Sall, EPSc);
  for (int i = 0; i < 32; ++i){
    int n = tid + i*256;
    float x = av[n] * f1;
    if (x >= PRUNEc){
      int id = atomicAdd(&cnt, 1);
      if (id < 1024){ lv[id] = x; li[id] = n; }
    }
  }
  __syncthreads();
  int L = cnt;
  float* tw = topw + bt*KS;
  int*   ti = topi + bt*KS;
  if (L == 0){
    if (tid < KS){ tw[tid] = (tid == 0) ? 1.f : 0.f; ti[tid] = (tid == 0) ? sArg : 0; }
    return;
  }
  if (L <= KS){
    if (tid < KS){ tw[tid] = (tid < L) ? lv[tid] : 0.f; ti[tid] = (tid < L) ? li[tid] : 0; }
    return;
  }
  for (int k = 0; k < KS; ++k){
    float bv = -1.f; int bn = 1<<30; int bp = -1;
    for (int j = tid; j < L; j += 256){
      float x = lv[j]; int nn = li[j];
      if (x > bv || (x == bv && nn < bn)){ bv = x; bn = nn; bp = j; }
    }
    #pragma unroll
    for (int off = 32; off; off >>= 1){
      float ov = __shfl_down(bv, off);
      int   on = __shfl_down(bn, off);
      int   op = __shfl_down(bp, off);
      if (ov > bv || (ov == bv && on < bn)){ bv = ov; bn = on; bp = op; }
    }
    if (lane == 0){ rv[wv] = bv; ri[wv] = bn; rp[wv] = bp; }
    __syncthreads();
    if (tid == 0){
      float bb = rv[0]; int bj = ri[0]; int pp = rp[0];
      for (int w2 = 1; w2 < 4; ++w2)
        if (rv[w2] > bb || (rv[w2] == bb && ri[w2] < bj)){ bb = rv[w2]; bj = ri[w2]; pp = rp[w2]; }
      tw[k] = bb; ti[k] = bj;
      lv[pp] = -1.f;
    }
    __syncthreads();
  }
}

// ---------- pooling: u = sum_k w_k*normed_k (LN folded via saved stats), then u@wv^T ----------
__global__ void tap_pool(const float* __restrict__ tokens, const float* __restrict__ ipw,
                         const float* __restrict__ ipb,
                         const float* __restrict__ pre_g, const float* __restrict__ pre_b,
                         const float* __restrict__ meanw, const float* __restrict__ invw,
                         const float* __restrict__ topw, const int* __restrict__ topi,
                         float* __restrict__ out){
  __shared__ float wk_[KS]; __shared__ int rk_[KS];
  __shared__ float coeff[KS];
  __shared__ __align__(16) float u[Dd];
  __shared__ float sW, sS;
  int bt = blockIdx.x;
  int b = bt >> 2;
  int tid = threadIdx.x;
  if (tid < KS){ wk_[tid] = topw[bt*KS + tid]; rk_[tid] = topi[bt*KS + tid]; }
  __syncthreads();
  if (tid < KS){
    float v = wk_[tid];
    #pragma unroll
    for (int off = 32; off; off >>= 1) v += __shfl_down(v, off);
    if (tid == 0) sW = v;
  }
  __syncthreads();
  float sumw = sW;
  float Winv = 1.0f / fmaxf(sumw, EPSc);
  float Wn   = sumw * Winv;
  if (tid < KS){
    int n = rk_[tid];
    float mk = meanw[(size_t)b*Nn + n];
    float ik = invw [(size_t)b*Nn + n];
    float wn = wk_[tid] * Winv;
    coeff[tid] = wn * ik;
    float sp = wn * mk * ik;
    #pragma unroll
    for (int off = 32; off; off >>= 1) sp += __shfl_down(sp, off);
    if (tid == 0) sS = sp;
  }
  __syncthreads();
  float Sv = sS;
  int d0 = tid, d1 = tid + 256;
  float acc0 = 0.f, acc1 = 0.f;
  #pragma unroll 4
  for (int k = 0; k < KS; ++k){
    float c = coeff[k];
    const float* xr = tokens + ((size_t)b*Nn + rk_[k])*Dd;
    acc0 = fmaf(c, xr[d0], acc0);
    acc1 = fmaf(c, xr[d1], acc1);
  }
  u[d0] = pre_g[d0]*(acc0 - Sv) + pre_b[d0]*Wn;
  u[d1] = pre_g[d1]*(acc1 - Sv) + pre_b[d1]*Wn;
  __syncthreads();
  const float4* u4 = (const float4*)u;
  const float4* w0 = (const float4*)(ipw + (size_t)(2*Dd + d0)*Dd);
  const float4* w1 = (const float4*)(ipw + (size_t)(2*Dd + d1)*Dd);
  float o0 = 0.f, o1 = 0.f;
  #pragma unroll 4
  for (int j4 = 0; j4 < 128; ++j4){
    float4 uu = u4[j4];
    float4 a = w0[j4], c = w1[j4];
    o0 += uu.x*a.x + uu.y*a.y + uu.z*a.z + uu.w*a.w;
    o1 += uu.x*c.x + uu.y*c.y + uu.z*c.z + uu.w*c.w;
  }
  out[bt*Dd + d0] = o0 + Wn*ipb[2*Dd + d0];
  out[bt*Dd + d1] = o1 + Wn*ipb[2*Dd + d1];
}

extern "C" void kernel_launch(void* const* d_in, const int* in_sizes, int n_in,
                              void* d_out, int out_size, void* d_ws, size_t ws_size,
                              hipStream_t stream){
  const float* tokens = (const float*)d_in[0];
  const void*  kpm    = d_in[1];
  const float* q      = (const float*)d_in[2];
  const float* ipw    = (const float*)d_in[3];
  const float* ipb    = (const float*)d_in[4];
  const float* pre_g  = (const float*)d_in[5];
  const float* pre_b  = (const float*)d_in[6];
  const float* q_g    = (const float*)d_in[7];
  const float* q_b    = (const float*)d_in[8];
  const float* ltau   = (const float*)d_in[9];
  char* ws = (char*)d_ws;
  float* C1    = (float*)(ws + WS_C1);
  float* C0    = (float*)(ws + WS_C0);
  float* mrow  = (float*)(ws + WS_M);
  float* lrow  = (float*)(ws + WS_L);
  float* topwv = (float*)(ws + WS_TOPW);
  int*   topiv = (int*)  (ws + WS_TOPI);
  int*   flag  = (int*)  (ws + WS_FLAG);
  unsigned short* G2h = (unsigned short*)(ws + WS_G2H);
  unsigned short* G2m = (unsigned short*)(ws + WS_G2M);
  unsigned short* G2l = (unsigned short*)(ws + WS_G2L);
  float* meanw = (float*)(ws + WS_MEAN);
  float* invw  = (float*)(ws + WS_INV);
  unsigned char* m8 = (unsigned char*)(ws + WS_MASK8);
  float* scores = (float*)(ws + WS_SCORES);
  float* out = (float*)d_out;

  hipLaunchKernelGGL(tap_detect, dim3(1), dim3(1024), 0, stream, (const uint4*)kpm, flag);
  hipLaunchKernelGGL(tap_mask,   dim3(NTOK/256), dim3(256), 0, stream, kpm, flag, m8);
  hipLaunchKernelGGL(tap_prep,   dim3(HTc), dim3(256), 0, stream,
                     q, ipw, ipb, pre_g, pre_b, q_g, q_b, ltau, G2h, G2m, G2l, C1, C0);
  hipLaunchKernelGGL(tap_scores, dim3(NTOK/128), dim3(256), 0, stream,
                     tokens, G2h, G2m, G2l, C1, C0, scores, meanw, invw);
  hipLaunchKernelGGL(tap_norm,   dim3(Bb*HTc), dim3(256), 0, stream, scores, m8, mrow, lrow);
  hipLaunchKernelGGL(tap_alpha,  dim3(Bb*Tt), dim3(256), 0, stream,
                     scores, m8, mrow, lrow, topwv, topiv);
  hipLaunchKernelGGL(tap_pool,   dim3(Bb*Tt), dim3(256), 0, stream,
                     tokens, ipw, ipb, pre_g, pre_b, meanw, invw, topwv, topiv, out);
}

// Round 3
// 589.055 us; speedup vs baseline: 1.1384x; 1.0266x over previous
//
#include <hip/hip_runtime.h>
#include <math.h>

#define Dd   512
#define Hh   8
#define Tt   4
#define HDd  64
#define Bb   16
#define Nn   8192
#define HTc  32
#define KS   64
#define NTOK (Bb*Nn)
#define PRUNEc 0.001f
#define EPSc   1e-8f

// ---- workspace byte offsets (~21 MiB; ws alloc is 1 GiB per fill evidence) ----
#define WS_C1     0u        // 32 f
#define WS_C0     128u      // 32 f
#define WS_M      2048u     // 512 f  global softmax row max
#define WS_L      4096u     // 512 f  global softmax row sum
#define WS_FLAG   6144u     // int (mask dtype flag)
#define WS_G2H    65536u    // 32*512 bf16 (hi split of g-scaled folded K-proj)
#define WS_G2M    98304u    // 32*512 bf16 (mid)
#define WS_G2L    131072u   // 32*512 bf16 (lo)
#define WS_MEAN   163840u   // 131072 f per-token LN mean
#define WS_INV    688128u   // 131072 f per-token LN rsqrt
#define WS_MASK8  1212416u  // 131072 bytes expanded mask
#define WS_PART   1343488u  // 4096 segs * 32 ht * float2 = 1 MiB (per-wave m,l)
#define WS_PEXP   4194304u  // 16 MiB p[b][ht][n] = exp(s - m_seg)

typedef __attribute__((ext_vector_type(8)))  short short8v;
typedef __attribute__((ext_vector_type(16))) float f32x16;

// bf16x3 split: x ~= h + m + l, each bf16-representable (trunc splits, exact residuals)
__device__ __forceinline__ void split3(float x, unsigned &h, unsigned &m, unsigned &l){
  unsigned u  = __float_as_uint(x);
  unsigned uh = u & 0xFFFF0000u;
  float rh = x - __uint_as_float(uh);
  unsigned um = __float_as_uint(rh) & 0xFFFF0000u;
  float rm = rh - __uint_as_float(um);
  unsigned ul = __float_as_uint(rm) & 0xFFFF0000u;
  h = uh; m = um; l = ul;
}

// 8 fp32 -> 3 bf16x8 fragment planes, fully in registers
__device__ __forceinline__ void split3x8(float4 v0, float4 v1,
                                         short8v &h, short8v &m, short8v &l){
  union { short8v s; unsigned u[4]; } H, M, L;
  float a[8] = {v0.x,v0.y,v0.z,v0.w,v1.x,v1.y,v1.z,v1.w};
  #pragma unroll
  for (int w = 0; w < 4; ++w){
    unsigned ha, ma, la, hb, mb, lb;
    split3(a[2*w],   ha, ma, la);
    split3(a[2*w+1], hb, mb, lb);
    H.u[w] = (ha>>16) | (hb & 0xFFFF0000u);
    M.u[w] = (ma>>16) | (mb & 0xFFFF0000u);
    L.u[w] = (la>>16) | (lb & 0xFFFF0000u);
  }
  h = H.s; m = M.s; l = L.s;
}

// ---------- mask dtype detection (bool may arrive as i32 / u8 / f32) ----------
__device__ __forceinline__ int chkw(unsigned v){
  return (v == 0x3f800000u) ? 2 : ((v & ~1u) ? 1 : 0);
}
__global__ void tap_detect(const uint4* mraw, int* flag){
  int tid = threadIdx.x;            // 1024 threads
  if (tid == 0) *flag = 0;
  __syncthreads();
  int f = 0;
  #pragma unroll
  for (int i = 0; i < 8; ++i){      // 8192 uint4 = first NTOK bytes
    uint4 v = mraw[tid + i*1024];
    f |= chkw(v.x) | chkw(v.y) | chkw(v.z) | chkw(v.w);
  }
  if (f) atomicOr(flag, f);
}

__global__ void tap_mask(const void* mraw, const int* flag, uchar4* m8){
  int i = blockIdx.x*256 + threadIdx.x;     // uchar4 index; grid = NTOK/1024
  int fl = *flag;
  uchar4 r;
  if (fl & 2){
    float4 v = ((const float4*)mraw)[i];
    r = make_uchar4(v.x != 0.f, v.y != 0.f, v.z != 0.f, v.w != 0.f);
  } else if (fl & 1){
    uchar4 v = ((const uchar4*)mraw)[i];
    r = make_uchar4(v.x != 0, v.y != 0, v.z != 0, v.w != 0);
  } else {
    int4 v = ((const int4*)mraw)[i];
    r = make_uchar4(v.x != 0, v.y != 0, v.z != 0, v.w != 0);
  }
  m8[i] = r;
}

// ---------- fold query path: G2 (bf16x3 split) [ht][j], C1[ht], C0[ht] ----------
// score[n][ht] = inv_n*(x_n . G2[ht] - mean_n*C1[ht]) + C0[ht]
__global__ void tap_prep(const float* q, const float* ipw, const float* ipb,
                         const float* pre_g, const float* pre_b,
                         const float* q_g, const float* q_b, const float* log_tau,
                         unsigned short* G2h, unsigned short* G2m, unsigned short* G2l,
                         float* C1, float* C0){
  __shared__ float query[Tt][Dd];
  __shared__ float qps[HDd];
  __shared__ float red[256];
  int tid = threadIdx.x;
  int ht = blockIdx.x;           // = h*T + t
  int h = ht >> 2, t = ht & 3;
  float tau = expf(log_tau[0]);
  tau = fminf(fmaxf(tau, 0.1f), 10.0f);
  float itau = 1.0f / tau;
  int wv = tid >> 6, lane = tid & 63;
  { // LN of q rows (wave per row)
    const float* qr = q + wv*Dd;
    float s = 0.f, ss = 0.f;
    for (int j = lane; j < Dd; j += 64){ float x = qr[j]; s += x; ss += x*x; }
    #pragma unroll
    for (int off = 32; off; off >>= 1){ s += __shfl_down(s, off); ss += __shfl_down(ss, off); }
    s = __shfl(s, 0); ss = __shfl(ss, 0);
    float mean = s * (1.f/Dd);
    float var  = ss * (1.f/Dd) - mean*mean;
    float inv  = rsqrtf(var + 1e-5f);
    for (int j = lane; j < Dd; j += 64){
      float x = qr[j];
      query[wv][j] = ((x - mean)*inv*q_g[j] + q_b[j]) * itau;
    }
  }
  __syncthreads();
  { // qp[d] = query[t] . wq[h*64+d] + bq   (4 threads per output)
    int d = tid >> 2, sub = tid & 3;
    int i = h*HDd + d;
    const float* wrow = ipw + (size_t)i*Dd;
    float acc = 0.f;
    int j0 = sub*128;
    for (int j = 0; j < 128; ++j) acc += query[t][j0+j]*wrow[j0+j];
    red[tid] = acc;
    __syncthreads();
    if (sub == 0) qps[d] = red[tid]+red[tid+1]+red[tid+2]+red[tid+3] + ipb[i];
    __syncthreads();
  }
  float c1p = 0.f, c0p = 0.f;
  for (int jj = 0; jj < 2; ++jj){
    int j = tid + jj*256;
    float acc = 0.f;
    #pragma unroll 8
    for (int d = 0; d < HDd; ++d)
      acc += qps[d] * ipw[(size_t)(Dd + h*HDd + d)*Dd + j];
    float w2 = acc * 0.125f;          // 1/sqrt(HD)
    float g2 = w2 * pre_g[j];
    unsigned uh, um, ul;
    split3(g2, uh, um, ul);
    G2h[ht*Dd + j] = (unsigned short)(uh >> 16);
    G2m[ht*Dd + j] = (unsigned short)(um >> 16);
    G2l[ht*Dd + j] = (unsigned short)(ul >> 16);
    // C1 must match the EFFECTIVE g used by the MFMA path (h+m+l)
    float geff = __uint_as_float(uh) + __uint_as_float(um) + __uint_as_float(ul);
    c1p += geff;
    c0p += w2 * pre_b[j];
  }
  if (tid < HDd) c0p += qps[tid] * ipb[Dd + h*HDd + tid] * 0.125f;  // bk term
  red[tid] = c1p; __syncthreads();
  for (int s = 128; s; s >>= 1){ if (tid < s) red[tid] += red[tid+s]; __syncthreads(); }
  if (tid == 0) C1[ht] = red[0];
  __syncthreads();
  red[tid] = c0p; __syncthreads();
  for (int s = 128; s; s >>= 1){ if (tid < s) red[tid] += red[tid+s]; __syncthreads(); }
  if (tid == 0) C0[ht] = red[0];
}

// ---------- main: LDS-free streaming bf16x3 MFMA scores + online-softmax partials ----------
// Tile: 128 tokens x 32 ht per block (4 waves, one 32x32 MFMA tile each).
// B-fragments load straight from global (2x float4/lane, 64B-aligned full lines);
// split3 -> bf16 planes in registers; A (G2 splits, 96 KB) L2-resident. No LDS,
// no barriers. Epilogue: per-wave 32-token segment (m,l) softmax partials via
// shfl_xor reduces; stores p = exp(s - m_seg) (masked -> 0) instead of raw s.
// exp is computed exactly ONCE per score element, on the VALU-idle MFMA kernel.
// C/D map (HW-verified): col(token) = lane&31, row(ht) = (r&3)+8*(r>>2)+4*(lane>>5).
__global__ __launch_bounds__(256, 4) void tap_scores(
    const float* __restrict__ tokens,
    const unsigned short* __restrict__ G2h, const unsigned short* __restrict__ G2m,
    const unsigned short* __restrict__ G2l,
    const float* __restrict__ C1, const float* __restrict__ C0,
    const unsigned char* __restrict__ m8,
    float* __restrict__ pexp, float2* __restrict__ part,
    float* __restrict__ meanw, float* __restrict__ invw){
  int tid   = threadIdx.x;
  int lane  = tid & 63, wv = tid >> 6;
  int col   = lane & 31;
  int bhalf = lane >> 5;
  size_t t0 = (size_t)blockIdx.x * 128;
  int brow  = (wv << 5) | col;           // this lane's token row in tile
  const float* __restrict__ xrow = tokens + (t0 + brow)*(size_t)Dd;
  int abase = (col << 9) | (bhalf << 3); // A row = ht = col, k-half offset

  f32x16 acc;
  #pragma unroll
  for (int i = 0; i < 16; ++i) acc[i] = 0.f;
  float ps = 0.f, pss = 0.f;

  for (int c = 0; c < 8; ++c){
    #pragma unroll
    for (int kc = 0; kc < 4; ++kc){
      int k0 = (c << 6) | (kc << 4) | (bhalf << 3);
      float4 v0 = *(const float4*)(xrow + k0);
      float4 v1 = *(const float4*)(xrow + k0 + 4);
      int ga = abase + (c << 6) + (kc << 4);
      short8v ah = *(const short8v*)(G2h + ga);
      short8v am = *(const short8v*)(G2m + ga);
      short8v al = *(const short8v*)(G2l + ga);
      ps  += v0.x+v0.y+v0.z+v0.w + v1.x+v1.y+v1.z+v1.w;
      pss += v0.x*v0.x+v0.y*v0.y+v0.z*v0.z+v0.w*v0.w
           + v1.x*v1.x+v1.y*v1.y+v1.z*v1.z+v1.w*v1.w;
      short8v bh, bm, bl;
      split3x8(v0, v1, bh, bm, bl);
      acc = __builtin_amdgcn_mfma_f32_32x32x16_bf16(ah, bh, acc, 0, 0, 0);
      acc = __builtin_amdgcn_mfma_f32_32x32x16_bf16(am, bh, acc, 0, 0, 0);
      acc = __builtin_amdgcn_mfma_f32_32x32x16_bf16(ah, bm, acc, 0, 0, 0);
      acc = __builtin_amdgcn_mfma_f32_32x32x16_bf16(am, bm, acc, 0, 0, 0);
      acc = __builtin_amdgcn_mfma_f32_32x32x16_bf16(al, bh, acc, 0, 0, 0);
      acc = __builtin_amdgcn_mfma_f32_32x32x16_bf16(ah, bl, acc, 0, 0, 0);
    }
  }
  // LN stats: merge with k-half sibling (lane ^ 32), then finalize per-lane
  ps  += __shfl_xor(ps, 32);
  pss += __shfl_xor(pss, 32);
  float mean = ps * (1.f/512.f);
  float var  = pss * (1.f/512.f) - mean*mean;
  float inv  = rsqrtf(var + 1e-5f);
  if (bhalf == 0){ meanw[t0 + brow] = mean; invw[t0 + brow] = inv; }
  unsigned char mko = m8[t0 + brow];
  int b = (int)(t0 >> 13);
  int n = (int)(t0 & 8191) + brow;
  int g = (int)blockIdx.x*4 + wv;        // global 32-token segment id
  #pragma unroll
  for (int r = 0; r < 16; ++r){
    int ht = (r & 3) + ((r >> 2) << 3) + (bhalf << 2);
    float sc = mko ? -1e30f : (inv*(acc[r] - mean*C1[ht]) + C0[ht]);
    float mx = sc;
    #pragma unroll
    for (int off = 16; off; off >>= 1) mx = fmaxf(mx, __shfl_xor(mx, off));
    float p = mko ? 0.f : __expf(sc - mx);
    float ls = p;
    #pragma unroll
    for (int off = 16; off; off >>= 1) ls += __shfl_xor(ls, off);
    pexp[(((size_t)(b*HTc + ht)) << 13) + n] = p;
    if (col == r) part[(size_t)g*HTc + ht] = make_float2(mx, ls);
  }
}

// ---------- combine per-segment (m,l) -> global row (M,L) ----------
__global__ void tap_combine(const float2* __restrict__ part,
                            float* __restrict__ mrow, float* __restrict__ lrow){
  int R = blockIdx.x;                    // b*32 + ht
  int b = R >> 5, ht = R & 31;
  int lane = threadIdx.x;                // 64
  const float2* pb = part + ((size_t)(b << 8))*HTc + ht;
  float2 v0 = pb[(size_t)(lane      )*HTc];
  float2 v1 = pb[(size_t)(lane +  64)*HTc];
  float2 v2 = pb[(size_t)(lane + 128)*HTc];
  float2 v3 = pb[(size_t)(lane + 192)*HTc];
  float M = fmaxf(fmaxf(v0.x, v1.x), fmaxf(v2.x, v3.x));
  #pragma unroll
  for (int off = 32; off; off >>= 1) M = fmaxf(M, __shfl_xor(M, off));
  float L = v0.y*__expf(v0.x - M) + v1.y*__expf(v1.x - M)
          + v2.y*__expf(v2.x - M) + v3.y*__expf(v3.x - M);
  #pragma unroll
  for (int off = 32; off; off >>= 1) L += __shfl_xor(L, off);
  if (lane == 0){ mrow[R] = M; lrow[R] = L; }
}

// ---------- fused: alpha (8 FMA/token, NO exp), prune, fallback, top-64, pool ----------
// a_n = sum_h p[h][n] * fac[h][seg(n)],  fac = exp(m_seg - M_h)/(8 L_h).
// topw/topi live in LDS; pool epilogue fused (u = sum w_k*normed_k, then u@wv^T).
__global__ __launch_bounds__(512, 1) void tap_select(
    const float* __restrict__ tokens, const float* __restrict__ ipw,
    const float* __restrict__ ipb,
    const float* __restrict__ pre_g, const float* __restrict__ pre_b,
    const float* __restrict__ pexp, const float2* __restrict__ part,
    const unsigned char* __restrict__ m8,
    const float* __restrict__ mrow, const float* __restrict__ lrow,
    const float* __restrict__ meanw, const float* __restrict__ invw,
    float* __restrict__ out){
  __shared__ float av[Nn];               // 32 KB
  __shared__ float fac[Hh][256];         // 8 KB
  __shared__ float lv[1024];             // 4 KB
  __shared__ int   li[1024];             // 4 KB
  __shared__ float tw[KS]; __shared__ int ti[KS];
  __shared__ float coeff[KS];
  __shared__ __align__(16) float u[Dd];
  __shared__ float rs[8];                       // lsum partials
  __shared__ float rva[8]; __shared__ int ria[8]; __shared__ int rpa[8];
  __shared__ int cnt; __shared__ int sArg; __shared__ float sW, sS;
  int bt = blockIdx.x;
  int b = bt >> 2, t = bt & 3;
  int tid = threadIdx.x, lane = tid & 63, wvi = tid >> 6;
  if (tid == 0) cnt = 0;
  // ---- per-(h,seg) factors
  #pragma unroll
  for (int j = 0; j < 4; ++j){
    int idx = tid + (j << 9);
    int h = idx >> 8, s = idx & 255;
    int R = b*HTc + h*Tt + t;
    float m  = part[((size_t)(b << 8) + s)*HTc + (h*Tt + t)].x;
    float Mr = mrow[R], Lr = lrow[R];
    fac[h][s] = (Lr > 0.f) ? __expf(m - Mr) * (0.125f / Lr) : 0.f;
  }
  const float* pr[Hh];
  #pragma unroll
  for (int h = 0; h < Hh; ++h)
    pr[h] = pexp + ((size_t)(b*HTc + h*Tt + t) << 13);
  const unsigned char* mk = m8 + b*Nn;
  __syncthreads();
  // ---- a_n, row sum, fallback argmax
  float lsum = 0.f;
  float bvv = -2.f; int bii = 1 << 30;
  #pragma unroll 2
  for (int i = 0; i < 16; ++i){
    int n = tid + (i << 9);
    float fs = fac[0][n >> 5]; // force LDS read AFTER barrier ordering (compiler ok)
    float a = pr[0][n] * fs;
    #pragma unroll
    for (int h = 1; h < Hh; ++h) a += pr[h][n] * fac[h][n >> 5];
    av[n] = a;
    lsum += a;
    float bb = mk[n] ? -1.f : a;
    if (bb > bvv || (bb == bvv && n < bii)){ bvv = bb; bii = n; }
  }
  #pragma unroll
  for (int off = 32; off; off >>= 1) lsum += __shfl_down(lsum, off);
  if (lane == 0) rs[wvi] = lsum;
  #pragma unroll
  for (int off = 32; off; off >>= 1){
    float ov = __shfl_down(bvv, off);
    int   oi = __shfl_down(bii, off);
    if (ov > bvv || (ov == bvv && oi < bii)){ bvv = ov; bii = oi; }
  }
  if (lane == 0){ rva[wvi] = bvv; ria[wvi] = bii; }
  __syncthreads();
  float Sall = rs[0]+rs[1]+rs[2]+rs[3]+rs[4]+rs[5]+rs[6]+rs[7];
  if (tid == 0){
    float bv2 = rva[0]; int bi2 = ria[0];
    for (int w2 = 1; w2 < 8; ++w2)
      if (rva[w2] > bv2 || (rva[w2] == bv2 && ria[w2] < bi2)){ bv2 = rva[w2]; bi2 = ria[w2]; }
    sArg = bi2;
  }
  float f1 = 1.0f / fmaxf(Sall, EPSc);
  // ---- compact survivors (normalized value >= PRUNE; at most 1000 since sum<=1)
  #pragma unroll 2
  for (int i = 0; i < 16; ++i){
    int n = tid + (i << 9);
    float x = av[n] * f1;
    if (x >= PRUNEc){
      int id = atomicAdd(&cnt, 1);
      if (id < 1024){ lv[id] = x; li[id] = n; }
    }
  }
  __syncthreads();
  int L = cnt;
  if (L == 0){                           // fallback: onehot at argmax
    if (tid == 0){ lv[0] = 1.f; li[0] = sArg; }
    L = 1;
    __syncthreads();
  }
  if (L <= KS){                          // all survivors selected; zero-fill rest
    if (tid < KS){ tw[tid] = (tid < L) ? lv[tid] : 0.f; ti[tid] = (tid < L) ? li[tid] : 0; }
    __syncthreads();
  } else {
    // exact top-64 (value desc, index asc) over short list (L <= 1000)
    for (int k = 0; k < KS; ++k){
      float bv = -1.f; int bn = 1 << 30; int bp = -1;
      for (int j = tid; j < L; j += 512){
        float x = lv[j]; int nn = li[j];
        if (x > bv || (x == bv && nn < bn)){ bv = x; bn = nn; bp = j; }
      }
      #pragma unroll
      for (int off = 32; off; off >>= 1){
        float ov = __shfl_down(bv, off);
        int   on = __shfl_down(bn, off);
        int   op = __shfl_down(bp, off);
        if (ov > bv || (ov == bv && on < bn)){ bv = ov; bn = on; bp = op; }
      }
      if (lane == 0){ rva[wvi] = bv; ria[wvi] = bn; rpa[wvi] = bp; }
      __syncthreads();
      if (tid == 0){
        float bb = rva[0]; int bj = ria[0]; int pp = rpa[0];
        for (int w2 = 1; w2 < 8; ++w2)
          if (rva[w2] > bb || (rva[w2] == bb && ria[w2] < bj)){ bb = rva[w2]; bj = ria[w2]; pp = rpa[w2]; }
        tw[k] = bb; ti[k] = bj;
        lv[pp] = -1.f;                   // consume
      }
      __syncthreads();
    }
  }
  // ---- pool epilogue (512 threads, one output dim each)
  if (wvi == 0){
    float v = tw[lane];
    #pragma unroll
    for (int off = 32; off; off >>= 1) v += __shfl_down(v, off);
    if (lane == 0) sW = v;
  }
  __syncthreads();
  float sumw = sW;
  float Winv = 1.0f / fmaxf(sumw, EPSc);
  float Wn   = sumw * Winv;
  if (wvi == 0){
    int n = ti[lane];
    float mk2 = meanw[(size_t)b*Nn + n];
    float ik  = invw [(size_t)b*Nn + n];
    float wn  = tw[lane] * Winv;
    coeff[lane] = wn * ik;
    float sp = wn * mk2 * ik;
    #pragma unroll
    for (int off = 32; off; off >>= 1) sp += __shfl_down(sp, off);
    if (lane == 0) sS = sp;
  }
  __syncthreads();
  float Sv = sS;
  int d = tid;
  float acc0 = 0.f;
  #pragma unroll 4
  for (int k = 0; k < KS; ++k){          // branchless: c==0 rows contribute 0
    float c = coeff[k];
    acc0 = fmaf(c, tokens[((size_t)b*Nn + ti[k])*Dd + d], acc0);
  }
  u[d] = pre_g[d]*(acc0 - Sv) + pre_b[d]*Wn;
  __syncthreads();
  const float4* u4 = (const float4*)u;
  const float4* w0 = (const float4*)(ipw + (size_t)(2*Dd + d)*Dd);
  float o0 = 0.f;
  #pragma unroll 4
  for (int j4 = 0; j4 < 128; ++j4){
    float4 uu = u4[j4];
    float4 a = w0[j4];
    o0 += uu.x*a.x + uu.y*a.y + uu.z*a.z + uu.w*a.w;
  }
  out[bt*Dd + d] = o0 + Wn*ipb[2*Dd + d];
}

extern "C" void kernel_launch(void* const* d_in, const int* in_sizes, int n_in,
                              void* d_out, int out_size, void* d_ws, size_t ws_size,
                              hipStream_t stream){
  const float* tokens = (const float*)d_in[0];
  const void*  kpm    = d_in[1];
  const float* q      = (const float*)d_in[2];
  const float* ipw    = (const float*)d_in[3];
  const float* ipb    = (const float*)d_in[4];
  const float* pre_g  = (const float*)d_in[5];
  const float* pre_b  = (const float*)d_in[6];
  const float* q_g    = (const float*)d_in[7];
  const float* q_b    = (const float*)d_in[8];
  const float* ltau   = (const float*)d_in[9];
  char* ws = (char*)d_ws;
  float* C1    = (float*)(ws + WS_C1);
  float* C0    = (float*)(ws + WS_C0);
  float* mrow  = (float*)(ws + WS_M);
  float* lrow  = (float*)(ws + WS_L);
  int*   flag  = (int*)  (ws + WS_FLAG);
  unsigned short* G2h = (unsigned short*)(ws + WS_G2H);
  unsigned short* G2m = (unsigned short*)(ws + WS_G2M);
  unsigned short* G2l = (unsigned short*)(ws + WS_G2L);
  float* meanw = (float*)(ws + WS_MEAN);
  float* invw  = (float*)(ws + WS_INV);
  unsigned char* m8 = (unsigned char*)(ws + WS_MASK8);
  float2* part = (float2*)(ws + WS_PART);
  float* pexp  = (float*)(ws + WS_PEXP);
  float* out = (float*)d_out;

  hipLaunchKernelGGL(tap_detect, dim3(1), dim3(1024), 0, stream, (const uint4*)kpm, flag);
  hipLaunchKernelGGL(tap_mask,   dim3(NTOK/1024), dim3(256), 0, stream, kpm, flag, (uchar4*)m8);
  hipLaunchKernelGGL(tap_prep,   dim3(HTc), dim3(256), 0, stream,
                     q, ipw, ipb, pre_g, pre_b, q_g, q_b, ltau, G2h, G2m, G2l, C1, C0);
  hipLaunchKernelGGL(tap_scores, dim3(NTOK/128), dim3(256), 0, stream,
                     tokens, G2h, G2m, G2l, C1, C0, m8, pexp, part, meanw, invw);
  hipLaunchKernelGGL(tap_combine, dim3(Bb*HTc), dim3(64), 0, stream, part, mrow, lrow);
  hipLaunchKernelGGL(tap_select, dim3(Bb*Tt), dim3(512), 0, stream,
                     tokens, ipw, ipb, pre_g, pre_b, pexp, part, m8,
                     mrow, lrow, meanw, invw, out);
}

// Round 4
// 573.734 us; speedup vs baseline: 1.1688x; 1.0267x over previous
//
#include <hip/hip_runtime.h>
#include <math.h>

#define Dd   512
#define Hh   8
#define Tt   4
#define HDd  64
#define Bb   16
#define Nn   8192
#define HTc  32
#define KS   64
#define NTOK (Bb*Nn)
#define PRUNEc 0.001f
#define EPSc   1e-8f

// ---- workspace byte offsets (~21 MiB; ws alloc is 1 GiB per fill evidence) ----
#define WS_C1     0u        // 32 f
#define WS_C0     128u      // 32 f
#define WS_FLAG   6144u     // int (mask dtype flag)
#define WS_G2H    65536u    // 32*512 bf16 (hi split of g-scaled folded K-proj)
#define WS_G2M    98304u    // 32*512 bf16 (mid)
#define WS_G2L    131072u   // 32*512 bf16 (lo)
#define WS_MEAN   163840u   // 131072 f per-token LN mean
#define WS_INV    688128u   // 131072 f per-token LN rsqrt
#define WS_PART   1343488u  // 4096 segs * 32 ht * float2 = 1 MiB (per-wave m,l)
#define WS_PEXP   4194304u  // 16 MiB p[b][ht][n] = exp(s - m_seg)

typedef __attribute__((ext_vector_type(8)))  short short8v;
typedef __attribute__((ext_vector_type(16))) float f32x16;

// bf16x3 split: x ~= h + m + l, each bf16-representable (trunc splits, exact residuals)
__device__ __forceinline__ void split3(float x, unsigned &h, unsigned &m, unsigned &l){
  unsigned u  = __float_as_uint(x);
  unsigned uh = u & 0xFFFF0000u;
  float rh = x - __uint_as_float(uh);
  unsigned um = __float_as_uint(rh) & 0xFFFF0000u;
  float rm = rh - __uint_as_float(um);
  unsigned ul = __float_as_uint(rm) & 0xFFFF0000u;
  h = uh; m = um; l = ul;
}

// 8 fp32 -> 3 bf16x8 fragment planes, fully in registers
__device__ __forceinline__ void split3x8(float4 v0, float4 v1,
                                         short8v &h, short8v &m, short8v &l){
  union { short8v s; unsigned u[4]; } H, M, L;
  float a[8] = {v0.x,v0.y,v0.z,v0.w,v1.x,v1.y,v1.z,v1.w};
  #pragma unroll
  for (int w = 0; w < 4; ++w){
    unsigned ha, ma, la, hb, mb, lb;
    split3(a[2*w],   ha, ma, la);
    split3(a[2*w+1], hb, mb, lb);
    H.u[w] = (ha>>16) | (hb & 0xFFFF0000u);
    M.u[w] = (ma>>16) | (mb & 0xFFFF0000u);
    L.u[w] = (la>>16) | (lb & 0xFFFF0000u);
  }
  h = H.s; m = M.s; l = L.s;
}

// per-element mask decode given dtype flag (2=f32, 1=u8, 0=i32)
__device__ __forceinline__ int mdecode(const void* mraw, int fl, size_t i){
  if (fl & 2) return ((const float*)mraw)[i] != 0.0f;
  if (fl & 1) return ((const unsigned char*)mraw)[i] != 0;
  return ((const int*)mraw)[i] != 0;
}

// ---------- mask dtype detection (bool may arrive as i32 / u8 / f32) ----------
__device__ __forceinline__ int chkw(unsigned v){
  return (v == 0x3f800000u) ? 2 : ((v & ~1u) ? 1 : 0);
}
__global__ void tap_detect(const uint4* mraw, int* flag){
  int tid = threadIdx.x;            // 1024 threads
  if (tid == 0) *flag = 0;
  __syncthreads();
  int f = 0;
  #pragma unroll
  for (int i = 0; i < 8; ++i){      // 8192 uint4 = first NTOK bytes (safe for all layouts)
    uint4 v = mraw[tid + i*1024];
    f |= chkw(v.x) | chkw(v.y) | chkw(v.z) | chkw(v.w);
  }
  if (f) atomicOr(flag, f);
}

// ---------- fold query path: G2 (bf16x3 split) [ht][j], C1[ht], C0[ht] ----------
// score[n][ht] = inv_n*(x_n . G2[ht] - mean_n*C1[ht]) + C0[ht]
__global__ void tap_prep(const float* q, const float* ipw, const float* ipb,
                         const float* pre_g, const float* pre_b,
                         const float* q_g, const float* q_b, const float* log_tau,
                         unsigned short* G2h, unsigned short* G2m, unsigned short* G2l,
                         float* C1, float* C0){
  __shared__ float query[Tt][Dd];
  __shared__ float qps[HDd];
  __shared__ float red[256];
  int tid = threadIdx.x;
  int ht = blockIdx.x;           // = h*T + t
  int h = ht >> 2, t = ht & 3;
  float tau = expf(log_tau[0]);
  tau = fminf(fmaxf(tau, 0.1f), 10.0f);
  float itau = 1.0f / tau;
  int wv = tid >> 6, lane = tid & 63;
  { // LN of q rows (wave per row)
    const float* qr = q + wv*Dd;
    float s = 0.f, ss = 0.f;
    for (int j = lane; j < Dd; j += 64){ float x = qr[j]; s += x; ss += x*x; }
    #pragma unroll
    for (int off = 32; off; off >>= 1){ s += __shfl_down(s, off); ss += __shfl_down(ss, off); }
    s = __shfl(s, 0); ss = __shfl(ss, 0);
    float mean = s * (1.f/Dd);
    float var  = ss * (1.f/Dd) - mean*mean;
    float inv  = rsqrtf(var + 1e-5f);
    for (int j = lane; j < Dd; j += 64){
      float x = qr[j];
      query[wv][j] = ((x - mean)*inv*q_g[j] + q_b[j]) * itau;
    }
  }
  __syncthreads();
  { // qp[d] = query[t] . wq[h*64+d] + bq   (4 threads per output)
    int d = tid >> 2, sub = tid & 3;
    int i = h*HDd + d;
    const float* wrow = ipw + (size_t)i*Dd;
    float acc = 0.f;
    int j0 = sub*128;
    for (int j = 0; j < 128; ++j) acc += query[t][j0+j]*wrow[j0+j];
    red[tid] = acc;
    __syncthreads();
    if (sub == 0) qps[d] = red[tid]+red[tid+1]+red[tid+2]+red[tid+3] + ipb[i];
    __syncthreads();
  }
  float c1p = 0.f, c0p = 0.f;
  for (int jj = 0; jj < 2; ++jj){
    int j = tid + jj*256;
    float acc = 0.f;
    #pragma unroll 8
    for (int d = 0; d < HDd; ++d)
      acc += qps[d] * ipw[(size_t)(Dd + h*HDd + d)*Dd + j];
    float w2 = acc * 0.125f;          // 1/sqrt(HD)
    float g2 = w2 * pre_g[j];
    unsigned uh, um, ul;
    split3(g2, uh, um, ul);
    G2h[ht*Dd + j] = (unsigned short)(uh >> 16);
    G2m[ht*Dd + j] = (unsigned short)(um >> 16);
    G2l[ht*Dd + j] = (unsigned short)(ul >> 16);
    // C1 must match the EFFECTIVE g used by the MFMA path (h+m+l)
    float geff = __uint_as_float(uh) + __uint_as_float(um) + __uint_as_float(ul);
    c1p += geff;
    c0p += w2 * pre_b[j];
  }
  if (tid < HDd) c0p += qps[tid] * ipb[Dd + h*HDd + tid] * 0.125f;  // bk term
  red[tid] = c1p; __syncthreads();
  for (int s = 128; s; s >>= 1){ if (tid < s) red[tid] += red[tid+s]; __syncthreads(); }
  if (tid == 0) C1[ht] = red[0];
  __syncthreads();
  red[tid] = c0p; __syncthreads();
  for (int s = 128; s; s >>= 1){ if (tid < s) red[tid] += red[tid+s]; __syncthreads(); }
  if (tid == 0) C0[ht] = red[0];
}

// ---------- main: LDS-free streaming bf16x3 MFMA scores + online-softmax partials ----------
// Tile: 128 tokens x 32 ht per block (4 waves, one 32x32 MFMA tile each).
// K flattened to 16 steps of 32 elems with an explicit register double-buffer:
// step s+1's token loads are issued BEFORE step s's split/MFMA cluster, so the
// ~900cy HBM latency hides under compute (4 waves/SIMD x ~456cy/step covers it).
// A (G2 splits, 96 KB) is L2-resident. No LDS, no barriers. Epilogue: per-wave
// 32-token-segment (m,l) softmax partials; stores p = exp(s - m_seg), masked->0.
// C/D map (HW-verified): col(token) = lane&31, row(ht) = (r&3)+8*(r>>2)+4*(lane>>5).
__global__ __launch_bounds__(256, 4) void tap_scores(
    const float* __restrict__ tokens,
    const unsigned short* __restrict__ G2h, const unsigned short* __restrict__ G2m,
    const unsigned short* __restrict__ G2l,
    const float* __restrict__ C1, const float* __restrict__ C0,
    const void* __restrict__ mraw, const int* __restrict__ flag,
    float* __restrict__ pexp, float2* __restrict__ part,
    float* __restrict__ meanw, float* __restrict__ invw){
  int tid   = threadIdx.x;
  int lane  = tid & 63, wv = tid >> 6;
  int col   = lane & 31;
  int bhalf = lane >> 5;
  size_t t0 = (size_t)blockIdx.x * 128;
  int brow  = (wv << 5) | col;           // this lane's token row in tile
  const float* __restrict__ xrow = tokens + (t0 + brow)*(size_t)Dd;
  int abase = (col << 9) | (bhalf << 3); // A row = ht = col, k-half offset

  f32x16 acc;
  #pragma unroll
  for (int i = 0; i < 16; ++i) acc[i] = 0.f;
  float ps = 0.f, pss = 0.f;

  float4 cv0[2], cv1[2];
  #pragma unroll
  for (int sub = 0; sub < 2; ++sub){
    int k0 = (sub << 4) | (bhalf << 3);
    cv0[sub] = *(const float4*)(xrow + k0);
    cv1[sub] = *(const float4*)(xrow + k0 + 4);
  }
  for (int s = 0; s < 16; ++s){
    float4 nv0[2], nv1[2];
    int sn = (s + 1) & 15;               // wrap: reloads L1-hot step 0 at the end
    #pragma unroll
    for (int sub = 0; sub < 2; ++sub){
      int k0 = (sn << 5) | (sub << 4) | (bhalf << 3);
      nv0[sub] = *(const float4*)(xrow + k0);
      nv1[sub] = *(const float4*)(xrow + k0 + 4);
    }
    #pragma unroll
    for (int sub = 0; sub < 2; ++sub){
      float4 v0 = cv0[sub], v1 = cv1[sub];
      int ga = abase + (s << 5) + (sub << 4);
      short8v ah = *(const short8v*)(G2h + ga);
      short8v am = *(const short8v*)(G2m + ga);
      short8v al = *(const short8v*)(G2l + ga);
      ps  += v0.x+v0.y+v0.z+v0.w + v1.x+v1.y+v1.z+v1.w;
      pss += v0.x*v0.x+v0.y*v0.y+v0.z*v0.z+v0.w*v0.w
           + v1.x*v1.x+v1.y*v1.y+v1.z*v1.z+v1.w*v1.w;
      short8v bh, bm, bl;
      split3x8(v0, v1, bh, bm, bl);
      acc = __builtin_amdgcn_mfma_f32_32x32x16_bf16(ah, bh, acc, 0, 0, 0);
      acc = __builtin_amdgcn_mfma_f32_32x32x16_bf16(am, bh, acc, 0, 0, 0);
      acc = __builtin_amdgcn_mfma_f32_32x32x16_bf16(ah, bm, acc, 0, 0, 0);
      acc = __builtin_amdgcn_mfma_f32_32x32x16_bf16(am, bm, acc, 0, 0, 0);
      acc = __builtin_amdgcn_mfma_f32_32x32x16_bf16(al, bh, acc, 0, 0, 0);
      acc = __builtin_amdgcn_mfma_f32_32x32x16_bf16(ah, bl, acc, 0, 0, 0);
    }
    #pragma unroll
    for (int sub = 0; sub < 2; ++sub){ cv0[sub] = nv0[sub]; cv1[sub] = nv1[sub]; }
  }
  // LN stats: merge with k-half sibling (lane ^ 32), then finalize per-lane
  ps  += __shfl_xor(ps, 32);
  pss += __shfl_xor(pss, 32);
  float mean = ps * (1.f/512.f);
  float var  = pss * (1.f/512.f) - mean*mean;
  float inv  = rsqrtf(var + 1e-5f);
  if (bhalf == 0){ meanw[t0 + brow] = mean; invw[t0 + brow] = inv; }
  int fl = *flag;
  int mko = mdecode(mraw, fl, t0 + brow);
  int b = (int)(t0 >> 13);
  int n = (int)(t0 & 8191) + brow;
  int g = (int)blockIdx.x*4 + wv;        // global 32-token segment id
  #pragma unroll
  for (int r = 0; r < 16; ++r){
    int ht = (r & 3) + ((r >> 2) << 3) + (bhalf << 2);
    float sc = mko ? -1e30f : (inv*(acc[r] - mean*C1[ht]) + C0[ht]);
    float mx = sc;
    #pragma unroll
    for (int off = 16; off; off >>= 1) mx = fmaxf(mx, __shfl_xor(mx, off));
    float p = mko ? 0.f : __expf(sc - mx);
    float ls = p;
    #pragma unroll
    for (int off = 16; off; off >>= 1) ls += __shfl_xor(ls, off);
    pexp[(((size_t)(b*HTc + ht)) << 13) + n] = p;
    if (col == r) part[(size_t)g*HTc + ht] = make_float2(mx, ls);
  }
}

// ---------- fused: (M,L) combine, alpha (8 FMA/token, NO exp), prune, fallback, top-64, pool ----------
// a_n = sum_h p[h][n] * fac[h][seg(n)],  fac = exp(m_seg - M_h)/(8 L_h).
__global__ __launch_bounds__(512, 1) void tap_select(
    const float* __restrict__ tokens, const float* __restrict__ ipw,
    const float* __restrict__ ipb,
    const float* __restrict__ pre_g, const float* __restrict__ pre_b,
    const float* __restrict__ pexp, const float2* __restrict__ part,
    const void* __restrict__ mraw, const int* __restrict__ flag,
    const float* __restrict__ meanw, const float* __restrict__ invw,
    float* __restrict__ out){
  __shared__ float av[Nn];               // 32 KB
  __shared__ float fac[Hh][256];         // 8 KB
  __shared__ float lv[1024];             // 4 KB
  __shared__ int   li[1024];             // 4 KB
  __shared__ float tw[KS]; __shared__ int ti[KS];
  __shared__ float coeff[KS];
  __shared__ __align__(16) float u[Dd];
  __shared__ float rs[8];                       // lsum partials
  __shared__ float rva[8]; __shared__ int ria[8]; __shared__ int rpa[8];
  __shared__ int cnt; __shared__ int sArg; __shared__ float sW, sS;
  int bt = blockIdx.x;
  int b = bt >> 2, t = bt & 3;
  int tid = threadIdx.x, lane = tid & 63, wvi = tid >> 6;
  int fl = *flag;
  if (tid == 0) cnt = 0;
  // ---- per-head global (M,L) from segment partials + fac table: wave h owns head h
  {
    int h = wvi;
    const float2* pb = part + ((size_t)(b << 8))*HTc + (h*Tt + t);
    float2 v0 = pb[(size_t)(lane      )*HTc];
    float2 v1 = pb[(size_t)(lane +  64)*HTc];
    float2 v2 = pb[(size_t)(lane + 128)*HTc];
    float2 v3 = pb[(size_t)(lane + 192)*HTc];
    float M = fmaxf(fmaxf(v0.x, v1.x), fmaxf(v2.x, v3.x));
    #pragma unroll
    for (int off = 32; off; off >>= 1) M = fmaxf(M, __shfl_xor(M, off));
    float L = v0.y*__expf(v0.x - M) + v1.y*__expf(v1.x - M)
            + v2.y*__expf(v2.x - M) + v3.y*__expf(v3.x - M);
    #pragma unroll
    for (int off = 32; off; off >>= 1) L += __shfl_xor(L, off);
    float inv8L = (L > 0.f) ? 0.125f / L : 0.f;
    fac[h][lane      ] = __expf(v0.x - M) * inv8L;
    fac[h][lane +  64] = __expf(v1.x - M) * inv8L;
    fac[h][lane + 128] = __expf(v2.x - M) * inv8L;
    fac[h][lane + 192] = __expf(v3.x - M) * inv8L;
  }
  const float* pr[Hh];
  #pragma unroll
  for (int h = 0; h < Hh; ++h)
    pr[h] = pexp + ((size_t)(b*HTc + h*Tt + t) << 13);
  __syncthreads();
  // ---- a_n, row sum, fallback argmax
  float lsum = 0.f;
  float bvv = -2.f; int bii = 1 << 30;
  #pragma unroll 2
  for (int i = 0; i < 16; ++i){
    int n = tid + (i << 9);
    float a = pr[0][n] * fac[0][n >> 5];
    #pragma unroll
    for (int h = 1; h < Hh; ++h) a += pr[h][n] * fac[h][n >> 5];
    av[n] = a;
    lsum += a;
    float bb = mdecode(mraw, fl, (size_t)b*Nn + n) ? -1.f : a;
    if (bb > bvv || (bb == bvv && n < bii)){ bvv = bb; bii = n; }
  }
  #pragma unroll
  for (int off = 32; off; off >>= 1) lsum += __shfl_down(lsum, off);
  if (lane == 0) rs[wvi] = lsum;
  #pragma unroll
  for (int off = 32; off; off >>= 1){
    float ov = __shfl_down(bvv, off);
    int   oi = __shfl_down(bii, off);
    if (ov > bvv || (ov == bvv && oi < bii)){ bvv = ov; bii = oi; }
  }
  if (lane == 0){ rva[wvi] = bvv; ria[wvi] = bii; }
  __syncthreads();
  float Sall = rs[0]+rs[1]+rs[2]+rs[3]+rs[4]+rs[5]+rs[6]+rs[7];
  if (tid == 0){
    float bv2 = rva[0]; int bi2 = ria[0];
    for (int w2 = 1; w2 < 8; ++w2)
      if (rva[w2] > bv2 || (rva[w2] == bv2 && ria[w2] < bi2)){ bv2 = rva[w2]; bi2 = ria[w2]; }
    sArg = bi2;
  }
  float f1 = 1.0f / fmaxf(Sall, EPSc);
  // ---- compact survivors (normalized value >= PRUNE; at most 1000 since sum<=1)
  #pragma unroll 2
  for (int i = 0; i < 16; ++i){
    int n = tid + (i << 9);
    float x = av[n] * f1;
    if (x >= PRUNEc){
      int id = atomicAdd(&cnt, 1);
      if (id < 1024){ lv[id] = x; li[id] = n; }
    }
  }
  __syncthreads();
  int L = cnt;
  if (L == 0){                           // fallback: onehot at argmax
    if (tid == 0){ lv[0] = 1.f; li[0] = sArg; }
    L = 1;
    __syncthreads();
  }
  if (L <= KS){                          // all survivors selected; zero-fill rest
    if (tid < KS){ tw[tid] = (tid < L) ? lv[tid] : 0.f; ti[tid] = (tid < L) ? li[tid] : 0; }
    __syncthreads();
  } else {
    // exact top-64 (value desc, index asc) over short list (L <= 1000)
    for (int k = 0; k < KS; ++k){
      float bv = -1.f; int bn = 1 << 30; int bp = -1;
      for (int j = tid; j < L; j += 512){
        float x = lv[j]; int nn = li[j];
        if (x > bv || (x == bv && nn < bn)){ bv = x; bn = nn; bp = j; }
      }
      #pragma unroll
      for (int off = 32; off; off >>= 1){
        float ov = __shfl_down(bv, off);
        int   on = __shfl_down(bn, off);
        int   op = __shfl_down(bp, off);
        if (ov > bv || (ov == bv && on < bn)){ bv = ov; bn = on; bp = op; }
      }
      if (lane == 0){ rva[wvi] = bv; ria[wvi] = bn; rpa[wvi] = bp; }
      __syncthreads();
      if (tid == 0){
        float bb = rva[0]; int bj = ria[0]; int pp = rpa[0];
        for (int w2 = 1; w2 < 8; ++w2)
          if (rva[w2] > bb || (rva[w2] == bb && ria[w2] < bj)){ bb = rva[w2]; bj = ria[w2]; pp = rpa[w2]; }
        tw[k] = bb; ti[k] = bj;
        lv[pp] = -1.f;                   // consume
      }
      __syncthreads();
    }
  }
  // ---- pool epilogue (512 threads, one output dim each)
  if (wvi == 0){
    float v = tw[lane];
    #pragma unroll
    for (int off = 32; off; off >>= 1) v += __shfl_down(v, off);
    if (lane == 0) sW = v;
  }
  __syncthreads();
  float sumw = sW;
  float Winv = 1.0f / fmaxf(sumw, EPSc);
  float Wn   = sumw * Winv;
  if (wvi == 0){
    int n = ti[lane];
    float mk2 = meanw[(size_t)b*Nn + n];
    float ik  = invw [(size_t)b*Nn + n];
    float wn  = tw[lane] * Winv;
    coeff[lane] = wn * ik;
    float sp = wn * mk2 * ik;
    #pragma unroll
    for (int off = 32; off; off >>= 1) sp += __shfl_down(sp, off);
    if (lane == 0) sS = sp;
  }
  __syncthreads();
  float Sv = sS;
  int d = tid;
  float acc0 = 0.f;
  #pragma unroll 4
  for (int k = 0; k < KS; ++k){          // branchless: c==0 rows contribute 0
    float c = coeff[k];
    acc0 = fmaf(c, tokens[((size_t)b*Nn + ti[k])*Dd + d], acc0);
  }
  u[d] = pre_g[d]*(acc0 - Sv) + pre_b[d]*Wn;
  __syncthreads();
  const float4* u4 = (const float4*)u;
  const float4* w0 = (const float4*)(ipw + (size_t)(2*Dd + d)*Dd);
  float o0 = 0.f;
  #pragma unroll 4
  for (int j4 = 0; j4 < 128; ++j4){
    float4 uu = u4[j4];
    float4 a = w0[j4];
    o0 += uu.x*a.x + uu.y*a.y + uu.z*a.z + uu.w*a.w;
  }
  out[bt*Dd + d] = o0 + Wn*ipb[2*Dd + d];
}

extern "C" void kernel_launch(void* const* d_in, const int* in_sizes, int n_in,
                              void* d_out, int out_size, void* d_ws, size_t ws_size,
                              hipStream_t stream){
  const float* tokens = (const float*)d_in[0];
  const void*  kpm    = d_in[1];
  const float* q      = (const float*)d_in[2];
  const float* ipw    = (const float*)d_in[3];
  const float* ipb    = (const float*)d_in[4];
  const float* pre_g  = (const float*)d_in[5];
  const float* pre_b  = (const float*)d_in[6];
  const float* q_g    = (const float*)d_in[7];
  const float* q_b    = (const float*)d_in[8];
  const float* ltau   = (const float*)d_in[9];
  char* ws = (char*)d_ws;
  float* C1    = (float*)(ws + WS_C1);
  float* C0    = (float*)(ws + WS_C0);
  int*   flag  = (int*)  (ws + WS_FLAG);
  unsigned short* G2h = (unsigned short*)(ws + WS_G2H);
  unsigned short* G2m = (unsigned short*)(ws + WS_G2M);
  unsigned short* G2l = (unsigned short*)(ws + WS_G2L);
  float* meanw = (float*)(ws + WS_MEAN);
  float* invw  = (float*)(ws + WS_INV);
  float2* part = (float2*)(ws + WS_PART);
  float* pexp  = (float*)(ws + WS_PEXP);
  float* out = (float*)d_out;

  hipLaunchKernelGGL(tap_detect, dim3(1), dim3(1024), 0, stream, (const uint4*)kpm, flag);
  hipLaunchKernelGGL(tap_prep,   dim3(HTc), dim3(256), 0, stream,
                     q, ipw, ipb, pre_g, pre_b, q_g, q_b, ltau, G2h, G2m, G2l, C1, C0);
  hipLaunchKernelGGL(tap_scores, dim3(NTOK/128), dim3(256), 0, stream,
                     tokens, G2h, G2m, G2l, C1, C0, kpm, flag, pexp, part, meanw, invw);
  hipLaunchKernelGGL(tap_select, dim3(Bb*Tt), dim3(512), 0, stream,
                     tokens, ipw, ipb, pre_g, pre_b, pexp, part, kpm, flag,
                     meanw, invw, out);
}

// Round 6
// 559.428 us; speedup vs baseline: 1.1987x; 1.0256x over previous
//
#include <hip/hip_runtime.h>
#include <math.h>

#define Dd   512
#define Hh   8
#define Tt   4
#define HDd  64
#define Bb   16
#define Nn   8192
#define HTc  32
#define KS   64
#define NTOK (Bb*Nn)
#define PRUNEc 0.001f
#define EPSc   1e-8f
#define TOKSC 16.0f          // token pre-scale for f16 split (residuals stay normal-range)

// ---- workspace byte offsets (~21 MiB; ws alloc is 1 GiB per fill evidence) ----
#define WS_C1     0u        // 32 f
#define WS_C0     128u      // 32 f
#define WS_CS     2048u     // 32 f  per-ht acc scale = escale/TOKSC
#define WS_FLAG   6144u     // int (mask dtype flag)
#define WS_G2H    65536u    // 32*512 f16 (hi split of row-normalized folded K-proj)
#define WS_G2L    98304u    // 32*512 f16 (lo split)
#define WS_MEAN   163840u   // 131072 f per-token LN mean
#define WS_INV    688128u   // 131072 f per-token LN rsqrt
#define WS_PART   1343488u  // 4096 segs * 32 ht * float2 = 1 MiB (per-wave m,l)
#define WS_PEXP   4194304u  // 16 MiB p[b][ht][n] = exp(s - m_seg)

typedef __attribute__((ext_vector_type(8)))  _Float16 half8v;
typedef __attribute__((ext_vector_type(2)))  __fp16   fp16x2;   // cvt_pkrtz's native type
typedef __attribute__((ext_vector_type(16))) float    f32x16;

// 8 f32 -> 2 f16x8 planes (h = rtz(x), l = rtz(x - h)); all-constant indexing
__device__ __forceinline__ void splitf16x8(float4 v0, float4 v1, half8v &h, half8v &l){
  union { half8v v; fp16x2 p[4]; } H, L;
  H.p[0] = __builtin_amdgcn_cvt_pkrtz(v0.x, v0.y);
  H.p[1] = __builtin_amdgcn_cvt_pkrtz(v0.z, v0.w);
  H.p[2] = __builtin_amdgcn_cvt_pkrtz(v1.x, v1.y);
  H.p[3] = __builtin_amdgcn_cvt_pkrtz(v1.z, v1.w);
  L.p[0] = __builtin_amdgcn_cvt_pkrtz(v0.x - (float)H.p[0][0], v0.y - (float)H.p[0][1]);
  L.p[1] = __builtin_amdgcn_cvt_pkrtz(v0.z - (float)H.p[1][0], v0.w - (float)H.p[1][1]);
  L.p[2] = __builtin_amdgcn_cvt_pkrtz(v1.x - (float)H.p[2][0], v1.y - (float)H.p[2][1]);
  L.p[3] = __builtin_amdgcn_cvt_pkrtz(v1.z - (float)H.p[3][0], v1.w - (float)H.p[3][1]);
  h = H.v; l = L.v;
}

// per-element mask decode given dtype flag (2=f32, 1=u8, 0=i32)
__device__ __forceinline__ int mdecode(const void* mraw, int fl, size_t i){
  if (fl & 2) return ((const float*)mraw)[i] != 0.0f;
  if (fl & 1) return ((const unsigned char*)mraw)[i] != 0;
  return ((const int*)mraw)[i] != 0;
}

__device__ __forceinline__ int chkw(unsigned v){
  return (v == 0x3f800000u) ? 2 : ((v & ~1u) ? 1 : 0);
}

// ---------- fold query path (blocks 0..31) + mask dtype detect (block 32) ----------
// score[n][ht] = inv_n*(x_n . G2eff[ht] - mean_n*C1[ht]) + C0[ht]
// G2eff = escale*(G2h + G2l); stored row-normalized f16 pair; CS = escale/TOKSC.
__global__ void tap_prep(const float* q, const float* ipw, const float* ipb,
                         const float* pre_g, const float* pre_b,
                         const float* q_g, const float* q_b, const float* log_tau,
                         const uint4* mraw, int* flag,
                         _Float16* G2h, _Float16* G2l,
                         float* C1, float* C0, float* CS){
  int tid = threadIdx.x;
  if (blockIdx.x == HTc){              // ---- detect role: bool may arrive i32/u8/f32
    if (tid == 0) *flag = 0;
    __syncthreads();
    int f = 0;
    #pragma unroll
    for (int i = 0; i < 32; ++i){      // 8192 uint4 = first NTOK bytes (safe all layouts)
      uint4 v = mraw[tid + i*256];
      f |= chkw(v.x) | chkw(v.y) | chkw(v.z) | chkw(v.w);
    }
    if (f) atomicOr(flag, f);
    return;
  }
  __shared__ float query[Tt][Dd];
  __shared__ float qps[HDd];
  __shared__ float red[256];
  __shared__ float g2row[Dd];
  __shared__ float escS;
  int ht = blockIdx.x;           // = h*T + t
  int h = ht >> 2, t = ht & 3;
  float tau = expf(log_tau[0]);
  tau = fminf(fmaxf(tau, 0.1f), 10.0f);
  float itau = 1.0f / tau;
  int wv = tid >> 6, lane = tid & 63;
  { // LN of q rows (wave per row)
    const float* qr = q + wv*Dd;
    float s = 0.f, ss = 0.f;
    for (int j = lane; j < Dd; j += 64){ float x = qr[j]; s += x; ss += x*x; }
    #pragma unroll
    for (int off = 32; off; off >>= 1){ s += __shfl_down(s, off); ss += __shfl_down(ss, off); }
    s = __shfl(s, 0); ss = __shfl(ss, 0);
    float mean = s * (1.f/Dd);
    float var  = ss * (1.f/Dd) - mean*mean;
    float inv  = rsqrtf(var + 1e-5f);
    for (int j = lane; j < Dd; j += 64){
      float x = qr[j];
      query[wv][j] = ((x - mean)*inv*q_g[j] + q_b[j]) * itau;
    }
  }
  __syncthreads();
  { // qp[d] = query[t] . wq[h*64+d] + bq   (4 threads per output)
    int d = tid >> 2, sub = tid & 3;
    int i = h*HDd + d;
    const float* wrow = ipw + (size_t)i*Dd;
    float acc = 0.f;
    int j0 = sub*128;
    for (int j = 0; j < 128; ++j) acc += query[t][j0+j]*wrow[j0+j];
    red[tid] = acc;
    __syncthreads();
    if (sub == 0) qps[d] = red[tid]+red[tid+1]+red[tid+2]+red[tid+3] + ipb[i];
    __syncthreads();
  }
  float c0p = 0.f;
  #pragma unroll
  for (int jj = 0; jj < 2; ++jj){
    int j = tid + jj*256;
    float acc = 0.f;
    #pragma unroll 8
    for (int d = 0; d < HDd; ++d)
      acc += qps[d] * ipw[(size_t)(Dd + h*HDd + d)*Dd + j];
    float w2 = acc * 0.125f;          // 1/sqrt(HD)
    g2row[j] = w2 * pre_g[j];
    c0p += w2 * pre_b[j];
  }
  if (tid < HDd) c0p += qps[tid] * ipb[Dd + h*HDd + tid] * 0.125f;  // bk term
  __syncthreads();
  { // row max -> pow2 escale (exact fold-back)
    float mx = fmaxf(fabsf(g2row[tid]), fabsf(g2row[tid + 256]));
    red[tid] = mx; __syncthreads();
    for (int s = 128; s; s >>= 1){ if (tid < s) red[tid] = fmaxf(red[tid], red[tid+s]); __syncthreads(); }
    if (tid == 0){
      float maxv = red[0];
      escS = (maxv > 0.f) ? exp2f(floorf(log2f(maxv))) : 1.f;
      CS[ht] = escS * (1.0f/TOKSC);
    }
    __syncthreads();
  }
  float esc = escS, ie = 1.0f/esc;
  float c1p = 0.f;
  #pragma unroll
  for (int jj = 0; jj < 2; ++jj){
    int j = tid + jj*256;
    float gs = g2row[j] * ie;
    _Float16 hh = (_Float16)gs;
    float r = gs - (float)hh;
    _Float16 ll = (_Float16)r;
    G2h[ht*Dd + j] = hh;
    G2l[ht*Dd + j] = ll;
    // C1 must match the EFFECTIVE g used by the MFMA path: esc*(h+l)
    c1p += esc*((float)hh + (float)ll);
  }
  red[tid] = c1p; __syncthreads();
  for (int s = 128; s; s >>= 1){ if (tid < s) red[tid] += red[tid+s]; __syncthreads(); }
  if (tid == 0) C1[ht] = red[0];
  __syncthreads();
  red[tid] = c0p; __syncthreads();
  for (int s = 128; s; s >>= 1){ if (tid < s) red[tid] += red[tid+s]; __syncthreads(); }
  if (tid == 0) C0[ht] = red[0];
}

// ---------- main: LDS-free streaming f16x2 MFMA scores + online-softmax partials ----------
// Tile: 128 tokens x 32 ht per block (4 waves, one 32x32 MFMA tile each).
// K in 16 steps of 32 elems; BOTH token (HBM) and A (L2) loads are register
// double-buffered and issued at step top, so the per-step wait covers loads
// that had a full step to land (no vmcnt drain of the prefetch).
// f16 2-split (h=rtz, l=rtz residual), all 4 cross-products kept -> error is
// representation-only ~2^-20; tokens pre-scaled x16 and G2 rows normalized by
// pow2 escale (folded back exactly via acc*CS[ht]) keep residuals normal-range.
// 8 MFMA/step vs 12 (bf16x3), A-planes 2 vs 3, split-VALU ~30% lighter.
// C/D map (HW-verified): col(token)=lane&31, row(ht)=(r&3)+8*(r>>2)+4*(lane>>5).
__global__ __launch_bounds__(256, 4) void tap_scores(
    const float* __restrict__ tokens,
    const _Float16* __restrict__ G2h, const _Float16* __restrict__ G2l,
    const float* __restrict__ C1, const float* __restrict__ C0,
    const float* __restrict__ CS,
    const void* __restrict__ mraw, const int* __restrict__ flag,
    float* __restrict__ pexp, float2* __restrict__ part,
    float* __restrict__ meanw, float* __restrict__ invw){
  int tid   = threadIdx.x;
  int lane  = tid & 63, wv = tid >> 6;
  int col   = lane & 31;
  int bhalf = lane >> 5;
  size_t t0 = (size_t)blockIdx.x * 128;
  int brow  = (wv << 5) | col;           // this lane's token row in tile
  const float* __restrict__ xrow = tokens + (t0 + brow)*(size_t)Dd;
  int abase = (col << 9) | (bhalf << 3); // A row = ht = col, k-half offset

  f32x16 acc;
  #pragma unroll
  for (int i = 0; i < 16; ++i) acc[i] = 0.f;
  float ps = 0.f, pss = 0.f;

  float4 cT0[2], cT1[2];
  half8v cAh[2], cAl[2];
  #pragma unroll
  for (int sub = 0; sub < 2; ++sub){
    int k0 = (sub << 4) | (bhalf << 3);
    cT0[sub] = *(const float4*)(xrow + k0);
    cT1[sub] = *(const float4*)(xrow + k0 + 4);
    cAh[sub] = *(const half8v*)(G2h + abase + (sub << 4));
    cAl[sub] = *(const half8v*)(G2l + abase + (sub << 4));
  }
  for (int s = 0; s < 16; ++s){
    float4 nT0[2], nT1[2];
    half8v nAh[2], nAl[2];
    int sn = (s + 1) & 15;               // wrap: reloads L1-hot step 0 at the end
    #pragma unroll
    for (int sub = 0; sub < 2; ++sub){
      int k0 = (sn << 5) | (sub << 4) | (bhalf << 3);
      nT0[sub] = *(const float4*)(xrow + k0);
      nT1[sub] = *(const float4*)(xrow + k0 + 4);
      int ga = abase + (sn << 5) + (sub << 4);
      nAh[sub] = *(const half8v*)(G2h + ga);
      nAl[sub] = *(const half8v*)(G2l + ga);
    }
    #pragma unroll
    for (int sub = 0; sub < 2; ++sub){
      float4 v0 = cT0[sub], v1 = cT1[sub];
      ps  += v0.x+v0.y+v0.z+v0.w + v1.x+v1.y+v1.z+v1.w;
      pss += v0.x*v0.x+v0.y*v0.y+v0.z*v0.z+v0.w*v0.w
           + v1.x*v1.x+v1.y*v1.y+v1.z*v1.z+v1.w*v1.w;
      float4 s0 = make_float4(v0.x*TOKSC, v0.y*TOKSC, v0.z*TOKSC, v0.w*TOKSC);
      float4 s1 = make_float4(v1.x*TOKSC, v1.y*TOKSC, v1.z*TOKSC, v1.w*TOKSC);
      half8v bh, bl;
      splitf16x8(s0, s1, bh, bl);
      half8v ah = cAh[sub], al = cAl[sub];
      acc = __builtin_amdgcn_mfma_f32_32x32x16_f16(ah, bh, acc, 0, 0, 0);
      acc = __builtin_amdgcn_mfma_f32_32x32x16_f16(ah, bl, acc, 0, 0, 0);
      acc = __builtin_amdgcn_mfma_f32_32x32x16_f16(al, bh, acc, 0, 0, 0);
      acc = __builtin_amdgcn_mfma_f32_32x32x16_f16(al, bl, acc, 0, 0, 0);
    }
    #pragma unroll
    for (int sub = 0; sub < 2; ++sub){
      cT0[sub] = nT0[sub]; cT1[sub] = nT1[sub];
      cAh[sub] = nAh[sub]; cAl[sub] = nAl[sub];
    }
  }
  // LN stats: merge with k-half sibling (lane ^ 32), then finalize per-lane
  ps  += __shfl_xor(ps, 32);
  pss += __shfl_xor(pss, 32);
  float mean = ps * (1.f/512.f);
  float var  = pss * (1.f/512.f) - mean*mean;
  float inv  = rsqrtf(var + 1e-5f);
  if (bhalf == 0){ meanw[t0 + brow] = mean; invw[t0 + brow] = inv; }
  int fl = *flag;
  int mko = mdecode(mraw, fl, t0 + brow);
  int b = (int)(t0 >> 13);
  int n = (int)(t0 & 8191) + brow;
  int g = (int)blockIdx.x*4 + wv;        // global 32-token segment id
  #pragma unroll
  for (int r = 0; r < 16; ++r){
    int ht = (r & 3) + ((r >> 2) << 3) + (bhalf << 2);
    float sc = mko ? -1e30f : (inv*(acc[r]*CS[ht] - mean*C1[ht]) + C0[ht]);
    float mx = sc;
    #pragma unroll
    for (int off = 16; off; off >>= 1) mx = fmaxf(mx, __shfl_xor(mx, off));
    float p = mko ? 0.f : __expf(sc - mx);
    float ls = p;
    #pragma unroll
    for (int off = 16; off; off >>= 1) ls += __shfl_xor(ls, off);
    pexp[(((size_t)(b*HTc + ht)) << 13) + n] = p;
    if (col == r) part[(size_t)g*HTc + ht] = make_float2(mx, ls);
  }
}

// ---------- fused: (M,L) combine, alpha (8 FMA/token, NO exp), prune, fallback, top-64, pool ----------
// a_n = sum_h p[h][n] * fac[h][seg(n)],  fac = exp(m_seg - M_h)/(8 L_h).
__global__ __launch_bounds__(512, 1) void tap_select(
    const float* __restrict__ tokens, const float* __restrict__ ipw,
    const float* __restrict__ ipb,
    const float* __restrict__ pre_g, const float* __restrict__ pre_b,
    const float* __restrict__ pexp, const float2* __restrict__ part,
    const void* __restrict__ mraw, const int* __restrict__ flag,
    const float* __restrict__ meanw, const float* __restrict__ invw,
    float* __restrict__ out){
  __shared__ float av[Nn];               // 32 KB
  __shared__ float fac[Hh][256];         // 8 KB
  __shared__ float lv[1024];             // 4 KB
  __shared__ int   li[1024];             // 4 KB
  __shared__ float tw[KS]; __shared__ int ti[KS];
  __shared__ float coeff[KS];
  __shared__ __align__(16) float u[Dd];
  __shared__ float rs[8];                       // lsum partials
  __shared__ float rva[8]; __shared__ int ria[8]; __shared__ int rpa[8];
  __shared__ int cnt; __shared__ int sArg; __shared__ float sW, sS;
  int bt = blockIdx.x;
  int b = bt >> 2, t = bt & 3;
  int tid = threadIdx.x, lane = tid & 63, wvi = tid >> 6;
  int fl = *flag;
  if (tid == 0) cnt = 0;
  // ---- per-head global (M,L) from segment partials + fac table: wave h owns head h
  {
    int h = wvi;
    const float2* pb = part + ((size_t)(b << 8))*HTc + (h*Tt + t);
    float2 v0 = pb[(size_t)(lane      )*HTc];
    float2 v1 = pb[(size_t)(lane +  64)*HTc];
    float2 v2 = pb[(size_t)(lane + 128)*HTc];
    float2 v3 = pb[(size_t)(lane + 192)*HTc];
    float M = fmaxf(fmaxf(v0.x, v1.x), fmaxf(v2.x, v3.x));
    #pragma unroll
    for (int off = 32; off; off >>= 1) M = fmaxf(M, __shfl_xor(M, off));
    float L = v0.y*__expf(v0.x - M) + v1.y*__expf(v1.x - M)
            + v2.y*__expf(v2.x - M) + v3.y*__expf(v3.x - M);
    #pragma unroll
    for (int off = 32; off; off >>= 1) L += __shfl_xor(L, off);
    float inv8L = (L > 0.f) ? 0.125f / L : 0.f;
    fac[h][lane      ] = __expf(v0.x - M) * inv8L;
    fac[h][lane +  64] = __expf(v1.x - M) * inv8L;
    fac[h][lane + 128] = __expf(v2.x - M) * inv8L;
    fac[h][lane + 192] = __expf(v3.x - M) * inv8L;
  }
  const float* pr[Hh];
  #pragma unroll
  for (int h = 0; h < Hh; ++h)
    pr[h] = pexp + ((size_t)(b*HTc + h*Tt + t) << 13);
  __syncthreads();
  // ---- a_n, row sum, fallback argmax
  float lsum = 0.f;
  float bvv = -2.f; int bii = 1 << 30;
  #pragma unroll 2
  for (int i = 0; i < 16; ++i){
    int n = tid + (i << 9);
    float a = pr[0][n] * fac[0][n >> 5];
    #pragma unroll
    for (int h = 1; h < Hh; ++h) a += pr[h][n] * fac[h][n >> 5];
    av[n] = a;
    lsum += a;
    float bb = mdecode(mraw, fl, (size_t)b*Nn + n) ? -1.f : a;
    if (bb > bvv || (bb == bvv && n < bii)){ bvv = bb; bii = n; }
  }
  #pragma unroll
  for (int off = 32; off; off >>= 1) lsum += __shfl_down(lsum, off);
  if (lane == 0) rs[wvi] = lsum;
  #pragma unroll
  for (int off = 32; off; off >>= 1){
    float ov = __shfl_down(bvv, off);
    int   oi = __shfl_down(bii, off);
    if (ov > bvv || (ov == bvv && oi < bii)){ bvv = ov; bii = oi; }
  }
  if (lane == 0){ rva[wvi] = bvv; ria[wvi] = bii; }
  __syncthreads();
  float Sall = rs[0]+rs[1]+rs[2]+rs[3]+rs[4]+rs[5]+rs[6]+rs[7];
  if (tid == 0){
    float bv2 = rva[0]; int bi2 = ria[0];
    for (int w2 = 1; w2 < 8; ++w2)
      if (rva[w2] > bv2 || (rva[w2] == bv2 && ria[w2] < bi2)){ bv2 = rva[w2]; bi2 = ria[w2]; }
    sArg = bi2;
  }
  float f1 = 1.0f / fmaxf(Sall, EPSc);
  // ---- compact survivors (normalized value >= PRUNE; at most 1000 since sum<=1)
  #pragma unroll 2
  for (int i = 0; i < 16; ++i){
    int n = tid + (i << 9);
    float x = av[n] * f1;
    if (x >= PRUNEc){
      int id = atomicAdd(&cnt, 1);
      if (id < 1024){ lv[id] = x; li[id] = n; }
    }
  }
  __syncthreads();
  int L = cnt;
  if (L == 0){                           // fallback: onehot at argmax
    if (tid == 0){ lv[0] = 1.f; li[0] = sArg; }
    L = 1;
    __syncthreads();
  }
  if (L <= KS){                          // all survivors selected; zero-fill rest
    if (tid < KS){ tw[tid] = (tid < L) ? lv[tid] : 0.f; ti[tid] = (tid < L) ? li[tid] : 0; }
    __syncthreads();
  } else {
    // exact top-64 (value desc, index asc) over short list (L <= 1000)
    for (int k = 0; k < KS; ++k){
      float bv = -1.f; int bn = 1 << 30; int bp = -1;
      for (int j = tid; j < L; j += 512){
        float x = lv[j]; int nn = li[j];
        if (x > bv || (x == bv && nn < bn)){ bv = x; bn = nn; bp = j; }
      }
      #pragma unroll
      for (int off = 32; off; off >>= 1){
        float ov = __shfl_down(bv, off);
        int   on = __shfl_down(bn, off);
        int   op = __shfl_down(bp, off);
        if (ov > bv || (ov == bv && on < bn)){ bv = ov; bn = on; bp = op; }
      }
      if (lane == 0){ rva[wvi] = bv; ria[wvi] = bn; rpa[wvi] = bp; }
      __syncthreads();
      if (tid == 0){
        float bb = rva[0]; int bj = ria[0]; int pp = rpa[0];
        for (int w2 = 1; w2 < 8; ++w2)
          if (rva[w2] > bb || (rva[w2] == bb && ria[w2] < bj)){ bb = rva[w2]; bj = ria[w2]; pp = rpa[w2]; }
        tw[k] = bb; ti[k] = bj;
        lv[pp] = -1.f;                   // consume
      }
      __syncthreads();
    }
  }
  // ---- pool epilogue (512 threads, one output dim each)
  if (wvi == 0){
    float v = tw[lane];
    #pragma unroll
    for (int off = 32; off; off >>= 1) v += __shfl_down(v, off);
    if (lane == 0) sW = v;
  }
  __syncthreads();
  float sumw = sW;
  float Winv = 1.0f / fmaxf(sumw, EPSc);
  float Wn   = sumw * Winv;
  if (wvi == 0){
    int n = ti[lane];
    float mk2 = meanw[(size_t)b*Nn + n];
    float ik  = invw [(size_t)b*Nn + n];
    float wn  = tw[lane] * Winv;
    coeff[lane] = wn * ik;
    float sp = wn * mk2 * ik;
    #pragma unroll
    for (int off = 32; off; off >>= 1) sp += __shfl_down(sp, off);
    if (lane == 0) sS = sp;
  }
  __syncthreads();
  float Sv = sS;
  int d = tid;
  float acc0 = 0.f;
  #pragma unroll 4
  for (int k = 0; k < KS; ++k){          // branchless: c==0 rows contribute 0
    float c = coeff[k];
    acc0 = fmaf(c, tokens[((size_t)b*Nn + ti[k])*Dd + d], acc0);
  }
  u[d] = pre_g[d]*(acc0 - Sv) + pre_b[d]*Wn;
  __syncthreads();
  const float4* u4 = (const float4*)u;
  const float4* w0 = (const float4*)(ipw + (size_t)(2*Dd + d)*Dd);
  float o0 = 0.f;
  #pragma unroll 4
  for (int j4 = 0; j4 < 128; ++j4){
    float4 uu = u4[j4];
    float4 a = w0[j4];
    o0 += uu.x*a.x + uu.y*a.y + uu.z*a.z + uu.w*a.w;
  }
  out[bt*Dd + d] = o0 + Wn*ipb[2*Dd + d];
}

extern "C" void kernel_launch(void* const* d_in, const int* in_sizes, int n_in,
                              void* d_out, int out_size, void* d_ws, size_t ws_size,
                              hipStream_t stream){
  const float* tokens = (const float*)d_in[0];
  const void*  kpm    = d_in[1];
  const float* q      = (const float*)d_in[2];
  const float* ipw    = (const float*)d_in[3];
  const float* ipb    = (const float*)d_in[4];
  const float* pre_g  = (const float*)d_in[5];
  const float* pre_b  = (const float*)d_in[6];
  const float* q_g    = (const float*)d_in[7];
  const float* q_b    = (const float*)d_in[8];
  const float* ltau   = (const float*)d_in[9];
  char* ws = (char*)d_ws;
  float* C1    = (float*)(ws + WS_C1);
  float* C0    = (float*)(ws + WS_C0);
  float* CSs   = (float*)(ws + WS_CS);
  int*   flag  = (int*)  (ws + WS_FLAG);
  _Float16* G2h = (_Float16*)(ws + WS_G2H);
  _Float16* G2l = (_Float16*)(ws + WS_G2L);
  float* meanw = (float*)(ws + WS_MEAN);
  float* invw  = (float*)(ws + WS_INV);
  float2* part = (float2*)(ws + WS_PART);
  float* pexp  = (float*)(ws + WS_PEXP);
  float* out = (float*)d_out;

  hipLaunchKernelGGL(tap_prep,   dim3(HTc + 1), dim3(256), 0, stream,
                     q, ipw, ipb, pre_g, pre_b, q_g, q_b, ltau,
                     (const uint4*)kpm, flag, G2h, G2l, C1, C0, CSs);
  hipLaunchKernelGGL(tap_scores, dim3(NTOK/128), dim3(256), 0, stream,
                     tokens, G2h, G2l, C1, C0, CSs, kpm, flag, pexp, part, meanw, invw);
  hipLaunchKernelGGL(tap_select, dim3(Bb*Tt), dim3(512), 0, stream,
                     tokens, ipw, ipb, pre_g, pre_b, pexp, part, kpm, flag,
                     meanw, invw, out);
}